// Round 12
// baseline (666.175 us; speedup 1.0000x reference)
//
#include <hip/hip_runtime.h>
#include <stdint.h>
#include <math.h>

#define NN 10000
#define NE 30000
#define NG 50
#define NH 8

typedef _Float16 f16;
typedef _Float16 f16x2 __attribute__((ext_vector_type(2)));
typedef _Float16 f16x4 __attribute__((ext_vector_type(4)));
typedef _Float16 f16x8 __attribute__((ext_vector_type(8)));
typedef float f32x4 __attribute__((ext_vector_type(4)));

// ---------------- helpers ----------------
__device__ inline void async16(f16* l, const f16* g) {
    __builtin_amdgcn_global_load_lds((const __attribute__((address_space(1))) void*)g,
                                     (__attribute__((address_space(3))) void*)l, 16, 0, 0);
}

// ---------------- CSR build ----------------
__global__ void hist_kernel(const int* __restrict__ dst, int* __restrict__ deg, int E) {
    int e = blockIdx.x * blockDim.x + threadIdx.x;
    if (e < E) atomicAdd(&deg[dst[e]], 1);
}

__global__ __launch_bounds__(1024) void scan_kernel(const int* __restrict__ deg, int* __restrict__ offs, int n) {
    __shared__ int tmp[1024];
    __shared__ int carry;
    if (threadIdx.x == 0) { carry = 0; offs[0] = 0; }
    __syncthreads();
    for (int base = 0; base < n; base += 1024) {
        int i = base + (int)threadIdx.x;
        int v = (i < n) ? deg[i] : 0;
        tmp[threadIdx.x] = v;
        __syncthreads();
        for (int d = 1; d < 1024; d <<= 1) {
            int t = 0;
            if ((int)threadIdx.x >= d) t = tmp[threadIdx.x - d];
            __syncthreads();
            if ((int)threadIdx.x >= d) tmp[threadIdx.x] += t;
            __syncthreads();
        }
        if (i < n) offs[i + 1] = carry + tmp[threadIdx.x];
        __syncthreads();
        if (threadIdx.x == 0) carry += tmp[1023];
        __syncthreads();
    }
}

__global__ void copy_int(const int* __restrict__ a, int* __restrict__ b, int n) {
    int i = blockIdx.x * blockDim.x + threadIdx.x;
    if (i < n) b[i] = a[i];
}

__global__ void scatter_kernel(const int* __restrict__ src, const int* __restrict__ dst,
                               int* __restrict__ cursor, int* __restrict__ srcCSR, int E) {
    int e = blockIdx.x * blockDim.x + threadIdx.x;
    if (e < E) {
        int p = atomicAdd(&cursor[dst[e]], 1);
        srcCSR[p] = src[e];
    }
}

// per-segment insertion sort -> deterministic CSR (fixed fp32 summation orders)
__global__ void sort_csr(const int* __restrict__ offs, int* __restrict__ srcCSR) {
    int n = blockIdx.x * blockDim.x + threadIdx.x;
    if (n >= NN) return;
    int s = offs[n], e = offs[n + 1];
    for (int i = s + 1; i < e; ++i) {
        int v = srcCSR[i];
        int j = i - 1;
        while (j >= s && srcCSR[j] > v) { srcCSR[j + 1] = srcCSR[j]; --j; }
        srcCSR[j + 1] = v;
    }
}

__global__ void goffs_kernel(const int* __restrict__ batch, int* __restrict__ goffs) {
    int g = threadIdx.x;
    if (g > NG) return;
    int lo = 0, hi = NN;
    while (lo < hi) {
        int mid = (lo + hi) >> 1;
        if (batch[mid] < g) lo = mid + 1; else hi = mid;
    }
    goffs[g] = lo;
}

// ---------------- conversions / weight prep ----------------
__global__ void cvt_f16_kernel(const float* __restrict__ in, f16* __restrict__ out, int n) {
    int i = blockIdx.x * blockDim.x + threadIdx.x;
    if (i < n) out[i] = (f16)in[i];
}

// Tiled-transpose weight prep: Bt[n][k] = f16(W(k,n)) with W = [W0 | W1 | 0-pad].
// 64x64 LDS tile -> coalesced global reads AND writes (prep2's strided reads were
// the hidden cost: 4B used per 128B line). +1 pad -> 2-way LDS banks (free).
__global__ __launch_bounds__(256) void prep2t(const float* __restrict__ W0, int n0,
                                              const float* __restrict__ W1, int n1,
                                              f16* __restrict__ Bt, int K, int Ntot) {
    __shared__ float tile[64][65];
    const int k0 = blockIdx.x * 64;
    const int nb = blockIdx.y * 64;
    const int tid = threadIdx.x;
    const int tn = tid & 63;
    const int t4 = tid >> 6;
#pragma unroll
    for (int i = 0; i < 16; ++i) {
        int kl = t4 + i * 4;
        int n = nb + tn;
        int k = k0 + kl;
        float w = 0.0f;
        if (n < n0) w = W0[(size_t)k * n0 + n];
        else if (n < n0 + n1) w = W1[(size_t)k * n1 + (n - n0)];
        tile[kl][tn] = w;
    }
    __syncthreads();
#pragma unroll
    for (int i = 0; i < 16; ++i) {
        int nl = t4 + i * 4;
        Bt[(size_t)(nb + nl) * K + k0 + tn] = (f16)tile[tn][nl];
    }
}

__global__ void biasK(const float* __restrict__ b0, int n0, const float* __restrict__ b1, int n1,
                      float* __restrict__ bias, int Ntot) {
    int n = blockIdx.x * 256 + threadIdx.x;
    if (n < Ntot) bias[n] = (n < n0) ? b0[n] : ((n < n0 + n1) ? b1[n - n0] : 0.0f);
}

// u/v rows of the Y transform, one wave per output (k,h,isV)
__global__ __launch_bounds__(256) void prepU(const float* __restrict__ qw, const float* __restrict__ qb,
                                             const float* __restrict__ kw, const float* __restrict__ kb,
                                             f16* __restrict__ BtY, float* __restrict__ biasY,
                                             int fin, int hc, int C) {
    const int wid = blockIdx.x * 4 + ((int)threadIdx.x >> 6);
    const int lane = threadIdx.x & 63;
    if (wid >= fin * 16) return;
    const int k = wid >> 4;
    const int idx = wid & 15;
    const int h = idx & 7, isV = idx >> 3;
    const float* W = isV ? kw : qw;
    const float* bvec = isV ? qb : kb;
    float s = 0.0f;
    for (int c = lane; c < C; c += 64) s += W[(size_t)k * hc + h * C + c] * bvec[h * C + c];
#pragma unroll
    for (int o = 32; o > 0; o >>= 1) s += __shfl_down(s, o, 64);
    if (lane == 0) BtY[(size_t)(8 * fin + isV * 8 + h) * fin + k] = (f16)s;
    if (wid < 8) {
        float cc = 0.0f;
        for (int c = lane; c < C; c += 64) cc += qb[wid * C + c] * kb[wid * C + c];
#pragma unroll
        for (int o = 32; o > 0; o >>= 1) cc += __shfl_down(cc, o, 64);
        if (lane == 0) biasY[8 * fin + wid] = cc;
    }
}

// ---------------- gemm128: 128x128 tile, 3-stage ring, vmcnt(4) ----------------
__global__ __launch_bounds__(256) void gemm128(const f16* __restrict__ A, int lda, int zA,
                                               const f16* __restrict__ Bt, int ldb, int zB,
                                               const float* __restrict__ bias,
                                               f16* __restrict__ C, int ldc, int zC,
                                               float* __restrict__ Sf,
                                               int M, int Np, int K, int hcS, int Sw) {
    __shared__ f16 smem[24576];   // 48 KB = 3 stages x (A 4096 + B 4096 f16)
    const int rm = blockIdx.x * 128;
    if (rm >= M) return;
    A  += (size_t)blockIdx.z * zA;
    Bt += (size_t)blockIdx.z * zB;
    C  += (size_t)blockIdx.z * zC;
    const int tid  = threadIdx.x;
    const int lane = tid & 63;
    const int wave = tid >> 6;
    const int l16  = lane & 15;
    const int quad = lane >> 4;
    const int cn   = blockIdx.y * 128;
    const int wrow = (wave >> 1) * 64;
    const int wcol = (wave & 1) * 64;

    const int rS  = tid >> 2;
    const int kc  = ((tid & 3) ^ ((tid >> 3) & 3)) << 3;
    int rowA0 = rm + rS;       if (rowA0 >= M) rowA0 = M - 1;
    int rowA1 = rm + rS + 64;  if (rowA1 >= M) rowA1 = M - 1;
    const f16* gA0 = A + (size_t)rowA0 * lda + kc;
    const f16* gA1 = A + (size_t)rowA1 * lda + kc;
    const f16* gB0 = Bt + (size_t)(cn + rS) * ldb + kc;
    const f16* gB1 = Bt + (size_t)(cn + rS + 64) * ldb + kc;

    const int swf = (l16 >> 1) & 3;
    const int rdAoff = (wrow + l16) * 32 + ((quad ^ swf) << 3);
    const int rdBoff = 4096 + (wcol + l16) * 32 + ((quad ^ swf) << 3);

    f32x4 acc[4][4] = {};

    auto stage_load = [&](int slot) {
        f16* base = smem + slot * 8192;
        async16(base + tid * 8, gA0);
        async16(base + tid * 8 + 2048, gA1);
        async16(base + 4096 + tid * 8, gB0);
        async16(base + 4096 + tid * 8 + 2048, gB1);
        gA0 += 32; gA1 += 32; gB0 += 32; gB1 += 32;
    };

    const int NI = K >> 5;
    stage_load(0);
    stage_load(1);

    int slot = 0;
    for (int i = 0; i < NI; ++i) {
        if (i + 1 < NI) asm volatile("s_waitcnt vmcnt(4)" ::: "memory");
        else            asm volatile("s_waitcnt vmcnt(0)" ::: "memory");
        asm volatile("s_barrier" ::: "memory");
        if (i + 2 < NI) {
            int s2 = slot + 2; if (s2 >= 3) s2 -= 3;
            stage_load(s2);
        }
        const f16* sb = smem + slot * 8192;
        f16x8 av[4], bv[4];
#pragma unroll
        for (int ii = 0; ii < 4; ++ii) av[ii] = *(const f16x8*)(sb + rdAoff + ii * 512);
#pragma unroll
        for (int j = 0; j < 4; ++j) bv[j] = *(const f16x8*)(sb + rdBoff + j * 512);
#pragma unroll
        for (int ii = 0; ii < 4; ++ii)
#pragma unroll
            for (int j = 0; j < 4; ++j)
                acc[ii][j] = __builtin_amdgcn_mfma_f32_16x16x32_f16(bv[j], av[ii], acc[ii][j], 0, 0, 0);
        ++slot; if (slot == 3) slot = 0;
    }
    __syncthreads();

    f16* sC = smem;    // 64 x 136 f16
    for (int round = 0; round < 2; ++round) {
        if ((wave >> 1) == round) {
#pragma unroll
            for (int j = 0; j < 4; ++j) {
                const int cb = wcol + j * 16 + quad * 4;
                const float4 bb = *(const float4*)(bias + cn + cb);
#pragma unroll
                for (int i = 0; i < 4; ++i) {
                    const int r = i * 16 + l16;
                    float v0 = acc[i][j][0] + bb.x;
                    float v1 = acc[i][j][1] + bb.y;
                    float v2 = acc[i][j][2] + bb.z;
                    float v3 = acc[i][j][3] + bb.w;
                    f16x4 o;
                    o[0] = (f16)v0; o[1] = (f16)v1; o[2] = (f16)v2; o[3] = (f16)v3;
                    *(f16x4*)(sC + r * 136 + cb) = o;
                    if (Sf) {
                        const int sc = cn + cb - hcS;
                        if (sc >= 0 && sc < Sw) {
                            const int grow = rm + round * 64 + r;
                            if (grow < M) {
                                float4 sv = { v0, v1, v2, v3 };
                                *(float4*)(Sf + (size_t)grow * Sw + sc) = sv;
                            }
                        }
                    }
                }
            }
        }
        __syncthreads();
#pragma unroll
        for (int it = 0; it < 4; ++it) {
            const int r = it * 16 + (tid >> 4);
            const int ch = tid & 15;
            const int grow = rm + round * 64 + r;
            if (grow < M) {
                f16x8 v = *(const f16x8*)(sC + r * 136 + ch * 8);
                *(f16x8*)(C + (size_t)grow * ldc + cn + ch * 8) = v;
            }
        }
        __syncthreads();
    }
}

// ---------------- gemm256: 128x256 tile, 64x128/wave (32 MFMA per 12 LDS reads:
// 375 B/MFMA vs 512 in gemm128 -> higher LDS-BW ceiling). 2-stage 48KB ring;
// prefetch issued after the barrier, waited one compute-phase later. Np%256==0.
__global__ __launch_bounds__(256) void gemm256(const f16* __restrict__ A, int lda,
                                               const f16* __restrict__ Bt, int ldb,
                                               const float* __restrict__ bias,
                                               f16* __restrict__ C, int ldc,
                                               float* __restrict__ Sf,
                                               int M, int Np, int K, int hcS, int Sw) {
    __shared__ f16 smem[24576];   // 48 KB = 2 stages x (A 4096 + B 8192 f16)
    const int rm = blockIdx.x * 128;
    if (rm >= M) return;
    const int tid  = threadIdx.x;
    const int lane = tid & 63;
    const int wave = tid >> 6;
    const int l16  = lane & 15;
    const int quad = lane >> 4;
    const int cn   = blockIdx.y * 256;
    const int wrow = (wave >> 1) * 64;
    const int wcol = (wave & 1) * 128;

    const int rS  = tid >> 2;
    const int kc  = ((tid & 3) ^ ((tid >> 3) & 3)) << 3;
    int rowA0 = rm + rS;       if (rowA0 >= M) rowA0 = M - 1;
    int rowA1 = rm + rS + 64;  if (rowA1 >= M) rowA1 = M - 1;
    const f16* gA0 = A + (size_t)rowA0 * lda + kc;
    const f16* gA1 = A + (size_t)rowA1 * lda + kc;
    const f16* gB0 = Bt + (size_t)(cn + rS) * ldb + kc;
    const f16* gB1 = Bt + (size_t)(cn + rS + 64) * ldb + kc;
    const f16* gB2 = Bt + (size_t)(cn + rS + 128) * ldb + kc;
    const f16* gB3 = Bt + (size_t)(cn + rS + 192) * ldb + kc;

    const int swf = (l16 >> 1) & 3;
    const int rdAoff = (wrow + l16) * 32 + ((quad ^ swf) << 3);
    const int rdBoff = 4096 + (wcol + l16) * 32 + ((quad ^ swf) << 3);

    f32x4 acc[8][4] = {};

    auto stage_load = [&](int slot) {
        f16* base = smem + slot * 12288;
        async16(base + tid * 8, gA0);
        async16(base + tid * 8 + 2048, gA1);
        f16* bb = base + 4096;
        async16(bb + tid * 8, gB0);
        async16(bb + tid * 8 + 2048, gB1);
        async16(bb + tid * 8 + 4096, gB2);
        async16(bb + tid * 8 + 6144, gB3);
        gA0 += 32; gA1 += 32; gB0 += 32; gB1 += 32; gB2 += 32; gB3 += 32;
    };

    const int NI = K >> 5;
    stage_load(0);

    int slot = 0;
    for (int i = 0; i < NI; ++i) {
        asm volatile("s_waitcnt vmcnt(0)" ::: "memory");  // stage i done (issued 1 phase ago)
        asm volatile("s_barrier" ::: "memory");
        if (i + 1 < NI) stage_load(slot ^ 1);             // lands during this compute phase
        const f16* sb = smem + slot * 12288;
        f16x8 av[4];
#pragma unroll
        for (int ii = 0; ii < 4; ++ii) av[ii] = *(const f16x8*)(sb + rdAoff + ii * 512);
#pragma unroll
        for (int j = 0; j < 8; ++j) {
            f16x8 bv = *(const f16x8*)(sb + rdBoff + j * 512);
#pragma unroll
            for (int ii = 0; ii < 4; ++ii)
                acc[j][ii] = __builtin_amdgcn_mfma_f32_16x16x32_f16(bv, av[ii], acc[j][ii], 0, 0, 0);
        }
        slot ^= 1;
    }
    __syncthreads();

    f16* sC = smem;    // 64 x 264 f16 (33 KB, unions staging)
    for (int round = 0; round < 2; ++round) {
        if ((wave >> 1) == round) {
#pragma unroll
            for (int j = 0; j < 8; ++j) {
                const int cb = wcol + j * 16 + quad * 4;
                const float4 bb = *(const float4*)(bias + cn + cb);
#pragma unroll
                for (int i = 0; i < 4; ++i) {
                    const int r = i * 16 + l16;
                    float v0 = acc[j][i][0] + bb.x;
                    float v1 = acc[j][i][1] + bb.y;
                    float v2 = acc[j][i][2] + bb.z;
                    float v3 = acc[j][i][3] + bb.w;
                    f16x4 o;
                    o[0] = (f16)v0; o[1] = (f16)v1; o[2] = (f16)v2; o[3] = (f16)v3;
                    *(f16x4*)(sC + r * 264 + cb) = o;
                    if (Sf) {
                        const int sc = cn + cb - hcS;
                        if (sc >= 0 && sc < Sw) {
                            const int grow = rm + round * 64 + r;
                            if (grow < M) {
                                float4 sv = { v0, v1, v2, v3 };
                                *(float4*)(Sf + (size_t)grow * Sw + sc) = sv;
                            }
                        }
                    }
                }
            }
        }
        __syncthreads();
#pragma unroll
        for (int it = 0; it < 8; ++it) {
            const int r = it * 8 + (tid >> 5);
            const int ch = tid & 31;
            const int grow = rm + round * 64 + r;
            if (grow < M) {
                f16x8 v = *(const f16x8*)(sC + r * 264 + ch * 8);
                *(f16x8*)(C + (size_t)grow * ldc + cn + ch * 8) = v;
            }
        }
        __syncthreads();
    }
}

// ---------------- layer-1 alpha via Y = X@M_h trick ----------------
__global__ __launch_bounds__(256) void alpha_fused_y(const f16* __restrict__ Y, const f16* __restrict__ X,
                                                     const int* __restrict__ offs,
                                                     const int* __restrict__ srcCSR,
                                                     float* __restrict__ alphaW,
                                                     int strideY, int fin, float scale) {
    const int n = blockIdx.x;
    const int e0 = offs[n];
    int d = offs[n + 1] - e0;
    if (d > 256) d = 256;

    __shared__ __align__(16) f16 sy[1024];
    __shared__ float sew[256 * NH];
    __shared__ float sv[256 * NH];
    __shared__ int sed[256];
    __shared__ float su[NH];
    const int tid = threadIdx.x;

    const f16* Yn = Y + (size_t)n * strideY;
    for (int c = tid; c < fin; c += 256) ((f16x8*)sy)[c] = ((const f16x8*)Yn)[c];
    if (tid < NH) su[tid] = (float)Yn[8 * fin + tid];
    for (int e = tid; e < d; e += 256) {
        int s = srcCSR[e0 + e];
        sed[e] = s;
        f16x8 vv = *(const f16x8*)(Y + (size_t)s * strideY + 8 * fin + 8);
#pragma unroll
        for (int t = 0; t < 8; ++t) sv[e * NH + t] = (float)vv[t];
    }
    __syncthreads();

    const int wv = tid >> 6, lane = tid & 63;
    const int cph = fin >> 3;
    const int csh = __ffs(cph) - 1;
    const int passes = fin >> 6;
    for (int e = wv; e < d; e += 4) {
        const f16x8* kg = (const f16x8*)(X + (size_t)sed[e] * fin);
        for (int p = 0; p < passes; ++p) {
            const int ci = p * 64 + lane;
            const int head = ci >> csh;
            const int kcn = ci & (cph - 1);
            f16x8 yv = ((const f16x8*)sy)[ci];
            f16x8 xv = kg[kcn];
            float acc = 0.0f;
#pragma unroll
            for (int t = 0; t < 8; ++t) acc += (float)yv[t] * (float)xv[t];
            for (int o = cph >> 1; o > 0; o >>= 1) acc += __shfl_down(acc, o, cph);
            if ((lane & (cph - 1)) == 0)
                sew[e * NH + head] = (acc + su[head] + sv[e * NH + head]) * scale;
        }
    }
    __syncthreads();

    if (tid < NH) {
        const int h = tid;
        float m = -3.0e38f;
        for (int e = 0; e < d; ++e) m = fmaxf(m, sew[e * NH + h]);
        float den = 0.0f;
        for (int e = 0; e < d; ++e) {
            float ex = __expf(sew[e * NH + h] - m);
            sew[e * NH + h] = ex;
            den += ex;
        }
        float inv = 1.0f / (fmaxf(den, 1e-16f) * (float)NH);
        for (int e = 0; e < d; ++e) sew[e * NH + h] *= inv;
    }
    __syncthreads();

    for (int i = tid; i < d * NH; i += 256) alphaW[(size_t)e0 * NH + i] = sew[i];
}

// ---------------- layers 2,3: edge logits + softmax from materialized Q|K ----------
__global__ __launch_bounds__(256) void alpha_fused(const f16* __restrict__ QK,
                                                   const int* __restrict__ offs,
                                                   const int* __restrict__ srcCSR,
                                                   float* __restrict__ alphaW,
                                                   int strideQK, int C, int hc, float scale) {
    const int n = blockIdx.x;
    const int e0 = offs[n];
    int d = offs[n + 1] - e0;
    if (d > 256) d = 256;

    __shared__ __align__(16) f16 sq[4096];
    __shared__ float sew[256 * NH];
    __shared__ int sed[256];
    const int tid = threadIdx.x;

    const f16x8* qg = (const f16x8*)(QK + (size_t)n * strideQK);
    const int qchunks = hc >> 3;
    for (int c = tid; c < qchunks; c += 256) ((f16x8*)sq)[c] = qg[c];
    for (int e = tid; e < d; e += 256) sed[e] = srcCSR[e0 + e];
    __syncthreads();

    const int wv = tid >> 6, lane = tid & 63;
    const int cph = C >> 3;
    const int passes = hc >> 9;
    for (int e = wv; e < d; e += 4) {
        const f16x8* kg = (const f16x8*)(QK + (size_t)sed[e] * strideQK + hc);
        for (int p = 0; p < passes; ++p) {
            const int ci = p * 64 + lane;
            f16x8 qv = ((const f16x8*)sq)[ci];
            f16x8 kv = kg[ci];
            float acc = 0.0f;
#pragma unroll
            for (int t = 0; t < 8; ++t) acc += (float)qv[t] * (float)kv[t];
            for (int o = cph >> 1; o > 0; o >>= 1) acc += __shfl_down(acc, o, cph);
            if ((lane & (cph - 1)) == 0) {
                const int head = ci / cph;
                sew[e * NH + head] = acc * scale;
            }
        }
    }
    __syncthreads();

    if (tid < NH) {
        const int h = tid;
        float m = -3.0e38f;
        for (int e = 0; e < d; ++e) m = fmaxf(m, sew[e * NH + h]);
        float den = 0.0f;
        for (int e = 0; e < d; ++e) {
            float ex = __expf(sew[e * NH + h] - m);
            sew[e * NH + h] = ex;
            den += ex;
        }
        float inv = 1.0f / (fmaxf(den, 1e-16f) * (float)NH);
        for (int e = 0; e < d; ++e) sew[e * NH + h] *= inv;
    }
    __syncthreads();

    for (int i = tid; i < d * NH; i += 256) alphaW[(size_t)e0 * NH + i] = sew[i];
}

// ---------------- per-node: weighted V aggregation + fp32 skip + ELU ----------------
__global__ __launch_bounds__(256) void node_agg(const f16* __restrict__ VS,
                                                const float* __restrict__ Sf,
                                                const int* __restrict__ offs,
                                                const int* __restrict__ srcCSR,
                                                const float* __restrict__ alphaW,
                                                float* __restrict__ hout, f16* __restrict__ houth,
                                                int C, int hc, int NpVS, int writeHout) {
    const int n = blockIdx.x;
    const int e0 = offs[n];
    int d = offs[n + 1] - e0;
    if (d > 256) d = 256;

    __shared__ float sew[256 * NH];
    __shared__ int sed[256];
    __shared__ float sred[512];
    const int tid = threadIdx.x;

    for (int i = tid; i < d * NH; i += 256) sew[i] = alphaW[(size_t)e0 * NH + i];
    for (int e = tid; e < d; e += 256) sed[e] = srcCSR[e0 + e];
    __syncthreads();

    const int half = C >> 1;
    const int cp = tid & (half - 1);
    const int grp = tid / half;
    const int ngr = 256 / half;
    float a0 = 0.0f, a1 = 0.0f;
    for (int e = grp; e < d; e += ngr) {
        const unsigned int* vp = (const unsigned int*)(VS + (size_t)sed[e] * NpVS);
#pragma unroll
        for (int h = 0; h < NH; ++h) {
            float w = sew[e * NH + h];
            f16x2 vv = __builtin_bit_cast(f16x2, vp[((h * C) >> 1) + cp]);
            a0 += w * (float)vv.x;
            a1 += w * (float)vv.y;
        }
    }
    if (ngr > 1) {
        sred[tid] = a0;
        sred[256 + tid] = a1;
        __syncthreads();
        if (grp == 0) {
            for (int g = 1; g < ngr; ++g) {
                a0 += sred[g * half + cp];
                a1 += sred[256 + g * half + cp];
            }
        }
    }
    if (grp == 0) {
        const int c = cp * 2;
        const float* Sp = Sf + (size_t)n * C;
        float o0 = a0 + Sp[c];
        float o1 = a1 + Sp[c + 1];
        o0 = o0 > 0.0f ? o0 : (__expf(o0) - 1.0f);
        o1 = o1 > 0.0f ? o1 : (__expf(o1) - 1.0f);
        if (writeHout) {
            hout[(size_t)n * C + c] = o0;
            hout[(size_t)n * C + c + 1] = o1;
        }
        houth[(size_t)n * C + c] = (f16)o0;
        houth[(size_t)n * C + c + 1] = (f16)o1;
    }
}

// ---------------- fused pooling + final FC: one block per graph, no atomics ----
__global__ __launch_bounds__(256) void pool_graph(const float* __restrict__ h,
                                                  const float* __restrict__ gw, const float* __restrict__ gb,
                                                  const float* __restrict__ fcw, const float* __restrict__ fcb,
                                                  const int* __restrict__ goffs,
                                                  float* __restrict__ gbuf, float* __restrict__ out) {
    const int g = blockIdx.x;
    const int s = goffs[g], e = goffs[g + 1];
    const int tid = threadIdx.x;
    const int wv = tid >> 6, lane = tid & 63;

    __shared__ float red[256];
    __shared__ float pl[64];
    __shared__ float sden;

    if (e == s) {
        if (tid < 10) out[g * 10 + tid] = fcb[tid];
        return;
    }

    const float gwl = gw[lane];
    for (int n = s + wv; n < e; n += 4) {
        float acc = h[(size_t)n * 64 + lane] * gwl;
#pragma unroll
        for (int o = 32; o > 0; o >>= 1) acc += __shfl_down(acc, o, 64);
        if (lane == 0) gbuf[n] = acc + gb[0];
    }
    __syncthreads();

    float m = -3.0e38f;
    for (int n = s + tid; n < e; n += 256) m = fmaxf(m, gbuf[n]);
    red[tid] = m;
    __syncthreads();
    for (int o = 128; o > 0; o >>= 1) {
        if (tid < o) red[tid] = fmaxf(red[tid], red[tid + o]);
        __syncthreads();
    }
    m = red[0];
    __syncthreads();

    float sum = 0.0f;
    for (int n = s + tid; n < e; n += 256) {
        float ex = __expf(gbuf[n] - m);
        gbuf[n] = ex;
        sum += ex;
    }
    red[tid] = sum;
    __syncthreads();
    for (int o = 128; o > 0; o >>= 1) {
        if (tid < o) red[tid] += red[tid + o];
        __syncthreads();
    }
    if (tid == 0) sden = 1.0f / fmaxf(red[0], 1e-16f);
    __syncthreads();

    float acc = 0.0f;
    for (int n = s + wv; n < e; n += 4) acc += gbuf[n] * h[(size_t)n * 64 + lane];
    red[tid] = acc;
    __syncthreads();
    if (wv == 0) pl[lane] = (red[lane] + red[64 + lane] + red[128 + lane] + red[192 + lane]) * sden;
    __syncthreads();

    if (tid < 10) {
        float o = fcb[tid];
#pragma unroll
        for (int c = 0; c < 64; ++c) o += pl[c] * fcw[c * 10 + tid];
        out[g * 10 + tid] = o;
    }
}

// ---------------- host ----------------
extern "C" void kernel_launch(void* const* d_in, const int* in_sizes, int n_in,
                              void* d_out, int out_size, void* d_ws, size_t ws_size,
                              hipStream_t stream) {
    const float* x   = (const float*)d_in[0];
    const int* ei    = (const int*)d_in[1];
    const int* src   = ei;
    const int* dst   = ei + NE;
    const int* batch = (const int*)d_in[2];

    struct LayerW { int fin, C, hc; const float *qw,*qb,*kw,*kb,*vw,*vb,*sw,*sb; };
    LayerW LW[3];
    const int fins[3]   = {128, 512, 256};
    const int Cs[3]     = {512, 256, 64};
    const int NpVS[3]   = {4608, 2304, 640};  // hc + C padded (L1,L2 %256; L3 %128)
    for (int l = 0; l < 3; ++l) {
        int b = 3 + 8 * l;
        LW[l].fin = fins[l]; LW[l].C = Cs[l]; LW[l].hc = Cs[l] * NH;
        LW[l].qw = (const float*)d_in[b + 0]; LW[l].qb = (const float*)d_in[b + 1];
        LW[l].kw = (const float*)d_in[b + 2]; LW[l].kb = (const float*)d_in[b + 3];
        LW[l].vw = (const float*)d_in[b + 4]; LW[l].vb = (const float*)d_in[b + 5];
        LW[l].sw = (const float*)d_in[b + 6]; LW[l].sb = (const float*)d_in[b + 7];
    }
    const float* gate_w = (const float*)d_in[27];
    const float* gate_b = (const float*)d_in[28];
    const float* fc_w   = (const float*)d_in[29];
    const float* fc_b   = (const float*)d_in[30];

    size_t off = 0;
    char* ws = (char*)d_ws;
    auto alloc = [&](size_t bytes) -> void* {
        void* p = ws + off;
        off = (off + bytes + 255) & ~(size_t)255;
        return p;
    };
    f16* BtQK   = (f16*)alloc((size_t)4096 * 512 * sizeof(f16));
    f16* BtVS   = (f16*)alloc((size_t)2304 * 512 * sizeof(f16));
    float* biasQK = (float*)alloc(8192 * sizeof(float));
    float* biasVS = (float*)alloc(4608 * sizeof(float));
    f16* QKbuf  = (f16*)alloc((size_t)NN * 4608 * sizeof(f16));    // Y / Q|K / V|S (per phase)
    float* Sf   = (float*)alloc((size_t)NN * 512 * sizeof(float)); // fp32 skip
    f16* xh     = (f16*)alloc((size_t)NN * 128 * sizeof(f16));
    f16* houth  = (f16*)alloc((size_t)NN * 512 * sizeof(f16));
    float* hf   = (float*)alloc((size_t)NN * 64 * sizeof(float));
    float* alphaW = (float*)alloc((size_t)NE * NH * sizeof(float));
    f16* qw16   = (f16*)alloc((size_t)128 * 4096 * sizeof(f16));
    f16* kw16   = (f16*)alloc((size_t)128 * 4096 * sizeof(f16));
    f16* BtY    = (f16*)alloc((size_t)1152 * 128 * sizeof(f16));
    float* biasY = (float*)alloc(1152 * sizeof(float));
    float* zbias = (float*)alloc(512 * sizeof(float));
    int* deg    = (int*)alloc(NN * sizeof(int));
    int* offs   = (int*)alloc((NN + 1) * sizeof(int));
    int* cursor = (int*)alloc(NN * sizeof(int));
    int* srcCSR = (int*)alloc(NE * sizeof(int));
    int* goffs  = (int*)alloc((NG + 1) * sizeof(int));
    float* gbuf = (float*)alloc(NN * sizeof(float));
    if (off > ws_size) return;

    // CSR build (+ deterministic sort) + graph offsets
    hipMemsetAsync(deg, 0, NN * sizeof(int), stream);
    hipMemsetAsync(zbias, 0, 512 * sizeof(float), stream);
    hipMemsetAsync(biasY, 0, 1152 * sizeof(float), stream);
    hist_kernel<<<(NE + 255) / 256, 256, 0, stream>>>(dst, deg, NE);
    scan_kernel<<<1, 1024, 0, stream>>>(deg, offs, NN);
    copy_int<<<(NN + 255) / 256, 256, 0, stream>>>(offs, cursor, NN);
    scatter_kernel<<<(NE + 255) / 256, 256, 0, stream>>>(src, dst, cursor, srcCSR, NE);
    sort_csr<<<(NN + 255) / 256, 256, 0, stream>>>(offs, srcCSR);
    goffs_kernel<<<1, 64, 0, stream>>>(batch, goffs);

    cvt_f16_kernel<<<(NN * 128 + 255) / 256, 256, 0, stream>>>(x, xh, NN * 128);

    const int grid_m = 80;   // mult of 8: XCD = blockIdx.x % 8 invariant across y-passes
    const f16* Acur = xh;
    for (int l = 0; l < 3; ++l) {
        const int K = LW[l].fin, C = LW[l].C, hc = LW[l].hc;
        const int Np1 = NpVS[l];
        const float scale = 1.0f / sqrtf((float)C);

        if (l == 0) {
            // ---- layer 1: Y = X @ [M_h | u | v] trick (fin=128 << hc=4096) ----
            const int fin = 128, NtotY = 1152;
            cvt_f16_kernel<<<(fin * hc + 255) / 256, 256, 0, stream>>>(LW[0].qw, qw16, fin * hc);
            cvt_f16_kernel<<<(fin * hc + 255) / 256, 256, 0, stream>>>(LW[0].kw, kw16, fin * hc);
            dim3 gm(1, 1, 8);
            gemm128<<<gm, 256, 0, stream>>>(kw16, hc, C, qw16, hc, C, zbias,
                                            BtY, fin, fin * fin, nullptr, fin, fin, C, 0, 0);
            prepU<<<(fin * 16 + 3) / 4, 256, 0, stream>>>(LW[0].qw, LW[0].qb, LW[0].kw, LW[0].kb,
                                                          BtY, biasY, fin, hc, C);
            dim3 gy(grid_m, NtotY / 128);
            gemm128<<<gy, 256, 0, stream>>>(xh, fin, 0, BtY, fin, 0, biasY,
                                            QKbuf, NtotY, 0, nullptr, NN, NtotY, fin, 0, 0);
            alpha_fused_y<<<NN, 256, 0, stream>>>(QKbuf, xh, offs, srcCSR, alphaW,
                                                  NtotY, fin, scale);
        } else {
            // ---- layers 2,3: materialized Q|K path ----
            const int Np0 = 2 * hc;   // 4096 (l=1), 1024 (l=2) -- both %256
            prep2t<<<dim3(K / 64, Np0 / 64), 256, 0, stream>>>(LW[l].qw, hc, LW[l].kw, hc,
                                                               BtQK, K, Np0);
            biasK<<<(Np0 + 255) / 256, 256, 0, stream>>>(LW[l].qb, hc, LW[l].kb, hc, biasQK, Np0);
            dim3 gqk(grid_m, Np0 / 256);
            gemm256<<<gqk, 256, 0, stream>>>(Acur, K, BtQK, K, biasQK,
                                             QKbuf, Np0, nullptr, NN, Np0, K, 0, 0);
            alpha_fused<<<NN, 256, 0, stream>>>(QKbuf, offs, srcCSR, alphaW, Np0, C, hc, scale);
        }

        // V|S GEMM reuses QKbuf (Y / Q|K dead after alpha)
        prep2t<<<dim3(K / 64, Np1 / 64), 256, 0, stream>>>(LW[l].vw, hc, LW[l].sw, C,
                                                           BtVS, K, Np1);
        biasK<<<(Np1 + 255) / 256, 256, 0, stream>>>(LW[l].vb, hc, LW[l].sb, C, biasVS, Np1);
        if (Np1 % 256 == 0) {
            dim3 gvs(grid_m, Np1 / 256);
            gemm256<<<gvs, 256, 0, stream>>>(Acur, K, BtVS, K, biasVS,
                                             QKbuf, Np1, Sf, NN, Np1, K, hc, C);
        } else {
            dim3 gvs(grid_m, Np1 / 128);
            gemm128<<<gvs, 256, 0, stream>>>(Acur, K, 0, BtVS, K, 0, biasVS,
                                             QKbuf, Np1, 0, Sf, NN, Np1, K, hc, C);
        }

        node_agg<<<NN, 256, 0, stream>>>(QKbuf, Sf, offs, srcCSR, alphaW, hf, houth,
                                         C, hc, Np1, l == 2 ? 1 : 0);
        Acur = houth;
    }

    pool_graph<<<NG, 256, 0, stream>>>(hf, gate_w, gate_b, fc_w, fc_b, goffs, gbuf, (float*)d_out);
}

// Round 13
// 565.001 us; speedup vs baseline: 1.1791x; 1.1791x over previous
//
#include <hip/hip_runtime.h>
#include <stdint.h>
#include <math.h>

#define NN 10000
#define NE 30000
#define NG 50
#define NH 8

typedef _Float16 f16;
typedef _Float16 f16x2 __attribute__((ext_vector_type(2)));
typedef _Float16 f16x4 __attribute__((ext_vector_type(4)));
typedef _Float16 f16x8 __attribute__((ext_vector_type(8)));
typedef float f32x4 __attribute__((ext_vector_type(4)));

// ---------------- helpers ----------------
__device__ inline void async16(f16* l, const f16* g) {
    __builtin_amdgcn_global_load_lds((const __attribute__((address_space(1))) void*)g,
                                     (__attribute__((address_space(3))) void*)l, 16, 0, 0);
}

// ---------------- CSR build ----------------
__global__ void hist_kernel(const int* __restrict__ dst, int* __restrict__ deg, int E) {
    int e = blockIdx.x * blockDim.x + threadIdx.x;
    if (e < E) atomicAdd(&deg[dst[e]], 1);
}

__global__ __launch_bounds__(1024) void scan_kernel(const int* __restrict__ deg, int* __restrict__ offs, int n) {
    __shared__ int tmp[1024];
    __shared__ int carry;
    if (threadIdx.x == 0) { carry = 0; offs[0] = 0; }
    __syncthreads();
    for (int base = 0; base < n; base += 1024) {
        int i = base + (int)threadIdx.x;
        int v = (i < n) ? deg[i] : 0;
        tmp[threadIdx.x] = v;
        __syncthreads();
        for (int d = 1; d < 1024; d <<= 1) {
            int t = 0;
            if ((int)threadIdx.x >= d) t = tmp[threadIdx.x - d];
            __syncthreads();
            if ((int)threadIdx.x >= d) tmp[threadIdx.x] += t;
            __syncthreads();
        }
        if (i < n) offs[i + 1] = carry + tmp[threadIdx.x];
        __syncthreads();
        if (threadIdx.x == 0) carry += tmp[1023];
        __syncthreads();
    }
}

__global__ void copy_int(const int* __restrict__ a, int* __restrict__ b, int n) {
    int i = blockIdx.x * blockDim.x + threadIdx.x;
    if (i < n) b[i] = a[i];
}

__global__ void scatter_kernel(const int* __restrict__ src, const int* __restrict__ dst,
                               int* __restrict__ cursor, int* __restrict__ srcCSR, int E) {
    int e = blockIdx.x * blockDim.x + threadIdx.x;
    if (e < E) {
        int p = atomicAdd(&cursor[dst[e]], 1);
        srcCSR[p] = src[e];
    }
}

// per-segment insertion sort -> deterministic CSR (fixed fp32 summation orders)
__global__ void sort_csr(const int* __restrict__ offs, int* __restrict__ srcCSR) {
    int n = blockIdx.x * blockDim.x + threadIdx.x;
    if (n >= NN) return;
    int s = offs[n], e = offs[n + 1];
    for (int i = s + 1; i < e; ++i) {
        int v = srcCSR[i];
        int j = i - 1;
        while (j >= s && srcCSR[j] > v) { srcCSR[j + 1] = srcCSR[j]; --j; }
        srcCSR[j + 1] = v;
    }
}

__global__ void goffs_kernel(const int* __restrict__ batch, int* __restrict__ goffs) {
    int g = threadIdx.x;
    if (g > NG) return;
    int lo = 0, hi = NN;
    while (lo < hi) {
        int mid = (lo + hi) >> 1;
        if (batch[mid] < g) lo = mid + 1; else hi = mid;
    }
    goffs[g] = lo;
}

// ---------------- conversions / weight prep ----------------
__global__ void cvt_f16_kernel(const float* __restrict__ in, f16* __restrict__ out, int n) {
    int i = blockIdx.x * blockDim.x + threadIdx.x;
    if (i < n) out[i] = (f16)in[i];
}

// Tiled-transpose weight prep: Bt[n][k] = f16(W(k,n)) with W = [W0 | W1 | 0-pad].
__global__ __launch_bounds__(256) void prep2t(const float* __restrict__ W0, int n0,
                                              const float* __restrict__ W1, int n1,
                                              f16* __restrict__ Bt, int K, int Ntot) {
    __shared__ float tile[64][65];
    const int k0 = blockIdx.x * 64;
    const int nb = blockIdx.y * 64;
    const int tid = threadIdx.x;
    const int tn = tid & 63;
    const int t4 = tid >> 6;
#pragma unroll
    for (int i = 0; i < 16; ++i) {
        int kl = t4 + i * 4;
        int n = nb + tn;
        int k = k0 + kl;
        float w = 0.0f;
        if (n < n0) w = W0[(size_t)k * n0 + n];
        else if (n < n0 + n1) w = W1[(size_t)k * n1 + (n - n0)];
        tile[kl][tn] = w;
    }
    __syncthreads();
#pragma unroll
    for (int i = 0; i < 16; ++i) {
        int nl = t4 + i * 4;
        Bt[(size_t)(nb + nl) * K + k0 + tn] = (f16)tile[tn][nl];
    }
}

__global__ void biasK(const float* __restrict__ b0, int n0, const float* __restrict__ b1, int n1,
                      float* __restrict__ bias, int Ntot) {
    int n = blockIdx.x * 256 + threadIdx.x;
    if (n < Ntot) bias[n] = (n < n0) ? b0[n] : ((n < n0 + n1) ? b1[n - n0] : 0.0f);
}

// u/v rows of the Y transform, one wave per output (k,h,isV)
__global__ __launch_bounds__(256) void prepU(const float* __restrict__ qw, const float* __restrict__ qb,
                                             const float* __restrict__ kw, const float* __restrict__ kb,
                                             f16* __restrict__ BtY, float* __restrict__ biasY,
                                             int fin, int hc, int C) {
    const int wid = blockIdx.x * 4 + ((int)threadIdx.x >> 6);
    const int lane = threadIdx.x & 63;
    if (wid >= fin * 16) return;
    const int k = wid >> 4;
    const int idx = wid & 15;
    const int h = idx & 7, isV = idx >> 3;
    const float* W = isV ? kw : qw;
    const float* bvec = isV ? qb : kb;
    float s = 0.0f;
    for (int c = lane; c < C; c += 64) s += W[(size_t)k * hc + h * C + c] * bvec[h * C + c];
#pragma unroll
    for (int o = 32; o > 0; o >>= 1) s += __shfl_down(s, o, 64);
    if (lane == 0) BtY[(size_t)(8 * fin + isV * 8 + h) * fin + k] = (f16)s;
    if (wid < 8) {
        float cc = 0.0f;
        for (int c = lane; c < C; c += 64) cc += qb[wid * C + c] * kb[wid * C + c];
#pragma unroll
        for (int o = 32; o > 0; o >>= 1) cc += __shfl_down(cc, o, 64);
        if (lane == 0) biasY[8 * fin + wid] = cc;
    }
}

// B for the layer-1 Z-GEMM: Bt2[c][k], K=1184.
// k<1024: (h=k>>7, f=k&127) -> vw[f, h*512+c] ; 1024..1151: sw[k-1024, c] ;
// 1152..1159: vb[(k-1152)*512+c] ; else 0. Tiled via LDS for coalesced writes.
__global__ __launch_bounds__(256) void prepZB(const float* __restrict__ vw, const float* __restrict__ sw,
                                              const float* __restrict__ vb, f16* __restrict__ Bt2) {
    __shared__ f16 tile[32][65];
    const int k0 = blockIdx.x * 32, c0 = blockIdx.y * 64;
    const int tid = threadIdx.x;
#pragma unroll
    for (int i = 0; i < 8; ++i) {
        int idx = tid + i * 256;
        int kl = idx >> 6, cl = idx & 63;
        int k = k0 + kl, c = c0 + cl;
        float v = 0.0f;
        if (k < 1024)      v = vw[(size_t)(k & 127) * 4096 + (k >> 7) * 512 + c];
        else if (k < 1152) v = sw[(size_t)(k - 1024) * 512 + c];
        else if (k < 1160) v = vb[(k - 1152) * 512 + c];
        tile[kl][cl] = (f16)v;
    }
    __syncthreads();
    const int cl = tid >> 2, kl = (tid & 3) * 8;
    f16x8 v;
#pragma unroll
    for (int t = 0; t < 8; ++t) v[t] = tile[kl + t][cl];
    *(f16x8*)(Bt2 + (size_t)(c0 + cl) * 1184 + k0 + kl) = v;
}

// ---------------- gemm128: 128x128 tile, 3-stage ring, vmcnt(4) ----------------
// act!=0 -> fused ELU on output.
__global__ __launch_bounds__(256) void gemm128(const f16* __restrict__ A, int lda, int zA,
                                               const f16* __restrict__ Bt, int ldb, int zB,
                                               const float* __restrict__ bias,
                                               f16* __restrict__ C, int ldc, int zC,
                                               float* __restrict__ Sf,
                                               int M, int Np, int K, int hcS, int Sw, int act) {
    __shared__ f16 smem[24576];   // 48 KB = 3 stages x (A 4096 + B 4096 f16)
    const int rm = blockIdx.x * 128;
    if (rm >= M) return;
    A  += (size_t)blockIdx.z * zA;
    Bt += (size_t)blockIdx.z * zB;
    C  += (size_t)blockIdx.z * zC;
    const int tid  = threadIdx.x;
    const int lane = tid & 63;
    const int wave = tid >> 6;
    const int l16  = lane & 15;
    const int quad = lane >> 4;
    const int cn   = blockIdx.y * 128;
    const int wrow = (wave >> 1) * 64;
    const int wcol = (wave & 1) * 64;

    const int rS  = tid >> 2;
    const int kc  = ((tid & 3) ^ ((tid >> 3) & 3)) << 3;
    int rowA0 = rm + rS;       if (rowA0 >= M) rowA0 = M - 1;
    int rowA1 = rm + rS + 64;  if (rowA1 >= M) rowA1 = M - 1;
    const f16* gA0 = A + (size_t)rowA0 * lda + kc;
    const f16* gA1 = A + (size_t)rowA1 * lda + kc;
    const f16* gB0 = Bt + (size_t)(cn + rS) * ldb + kc;
    const f16* gB1 = Bt + (size_t)(cn + rS + 64) * ldb + kc;

    const int swf = (l16 >> 1) & 3;
    const int rdAoff = (wrow + l16) * 32 + ((quad ^ swf) << 3);
    const int rdBoff = 4096 + (wcol + l16) * 32 + ((quad ^ swf) << 3);

    f32x4 acc[4][4] = {};

    auto stage_load = [&](int slot) {
        f16* base = smem + slot * 8192;
        async16(base + tid * 8, gA0);
        async16(base + tid * 8 + 2048, gA1);
        async16(base + 4096 + tid * 8, gB0);
        async16(base + 4096 + tid * 8 + 2048, gB1);
        gA0 += 32; gA1 += 32; gB0 += 32; gB1 += 32;
    };

    const int NI = K >> 5;
    stage_load(0);
    stage_load(1);

    int slot = 0;
    for (int i = 0; i < NI; ++i) {
        if (i + 1 < NI) asm volatile("s_waitcnt vmcnt(4)" ::: "memory");
        else            asm volatile("s_waitcnt vmcnt(0)" ::: "memory");
        asm volatile("s_barrier" ::: "memory");
        if (i + 2 < NI) {
            int s2 = slot + 2; if (s2 >= 3) s2 -= 3;
            stage_load(s2);
        }
        const f16* sb = smem + slot * 8192;
        f16x8 av[4], bv[4];
#pragma unroll
        for (int ii = 0; ii < 4; ++ii) av[ii] = *(const f16x8*)(sb + rdAoff + ii * 512);
#pragma unroll
        for (int j = 0; j < 4; ++j) bv[j] = *(const f16x8*)(sb + rdBoff + j * 512);
#pragma unroll
        for (int ii = 0; ii < 4; ++ii)
#pragma unroll
            for (int j = 0; j < 4; ++j)
                acc[ii][j] = __builtin_amdgcn_mfma_f32_16x16x32_f16(bv[j], av[ii], acc[ii][j], 0, 0, 0);
        ++slot; if (slot == 3) slot = 0;
    }
    __syncthreads();

    f16* sC = smem;    // 64 x 136 f16
    for (int round = 0; round < 2; ++round) {
        if ((wave >> 1) == round) {
#pragma unroll
            for (int j = 0; j < 4; ++j) {
                const int cb = wcol + j * 16 + quad * 4;
                const float4 bb = *(const float4*)(bias + cn + cb);
#pragma unroll
                for (int i = 0; i < 4; ++i) {
                    const int r = i * 16 + l16;
                    float v0 = acc[i][j][0] + bb.x;
                    float v1 = acc[i][j][1] + bb.y;
                    float v2 = acc[i][j][2] + bb.z;
                    float v3 = acc[i][j][3] + bb.w;
                    if (act) {
                        v0 = v0 > 0.0f ? v0 : (__expf(v0) - 1.0f);
                        v1 = v1 > 0.0f ? v1 : (__expf(v1) - 1.0f);
                        v2 = v2 > 0.0f ? v2 : (__expf(v2) - 1.0f);
                        v3 = v3 > 0.0f ? v3 : (__expf(v3) - 1.0f);
                    }
                    f16x4 o;
                    o[0] = (f16)v0; o[1] = (f16)v1; o[2] = (f16)v2; o[3] = (f16)v3;
                    *(f16x4*)(sC + r * 136 + cb) = o;
                    if (Sf) {
                        const int sc = cn + cb - hcS;
                        if (sc >= 0 && sc < Sw) {
                            const int grow = rm + round * 64 + r;
                            if (grow < M) {
                                float4 sv = { v0, v1, v2, v3 };
                                *(float4*)(Sf + (size_t)grow * Sw + sc) = sv;
                            }
                        }
                    }
                }
            }
        }
        __syncthreads();
#pragma unroll
        for (int it = 0; it < 4; ++it) {
            const int r = it * 16 + (tid >> 4);
            const int ch = tid & 15;
            const int grow = rm + round * 64 + r;
            if (grow < M) {
                f16x8 v = *(const f16x8*)(sC + r * 136 + ch * 8);
                *(f16x8*)(C + (size_t)grow * ldc + cn + ch * 8) = v;
            }
        }
        __syncthreads();
    }
}

// ---------------- layer-1 alpha via Y = X@M_h trick ----------------
__global__ __launch_bounds__(256) void alpha_fused_y(const f16* __restrict__ Y, const f16* __restrict__ X,
                                                     const int* __restrict__ offs,
                                                     const int* __restrict__ srcCSR,
                                                     float* __restrict__ alphaW,
                                                     int strideY, int fin, float scale) {
    const int n = blockIdx.x;
    const int e0 = offs[n];
    int d = offs[n + 1] - e0;
    if (d > 256) d = 256;

    __shared__ __align__(16) f16 sy[1024];
    __shared__ float sew[256 * NH];
    __shared__ float sv[256 * NH];
    __shared__ int sed[256];
    __shared__ float su[NH];
    const int tid = threadIdx.x;

    const f16* Yn = Y + (size_t)n * strideY;
    for (int c = tid; c < fin; c += 256) ((f16x8*)sy)[c] = ((const f16x8*)Yn)[c];
    if (tid < NH) su[tid] = (float)Yn[8 * fin + tid];
    for (int e = tid; e < d; e += 256) {
        int s = srcCSR[e0 + e];
        sed[e] = s;
        f16x8 vv = *(const f16x8*)(Y + (size_t)s * strideY + 8 * fin + 8);
#pragma unroll
        for (int t = 0; t < 8; ++t) sv[e * NH + t] = (float)vv[t];
    }
    __syncthreads();

    const int wv = tid >> 6, lane = tid & 63;
    const int cph = fin >> 3;
    const int csh = __ffs(cph) - 1;
    const int passes = fin >> 6;
    for (int e = wv; e < d; e += 4) {
        const f16x8* kg = (const f16x8*)(X + (size_t)sed[e] * fin);
        for (int p = 0; p < passes; ++p) {
            const int ci = p * 64 + lane;
            const int head = ci >> csh;
            const int kcn = ci & (cph - 1);
            f16x8 yv = ((const f16x8*)sy)[ci];
            f16x8 xv = kg[kcn];
            float acc = 0.0f;
#pragma unroll
            for (int t = 0; t < 8; ++t) acc += (float)yv[t] * (float)xv[t];
            for (int o = cph >> 1; o > 0; o >>= 1) acc += __shfl_down(acc, o, cph);
            if ((lane & (cph - 1)) == 0)
                sew[e * NH + head] = (acc + su[head] + sv[e * NH + head]) * scale;
        }
    }
    __syncthreads();

    if (tid < NH) {
        const int h = tid;
        float m = -3.0e38f;
        for (int e = 0; e < d; ++e) m = fmaxf(m, sew[e * NH + h]);
        float den = 0.0f;
        for (int e = 0; e < d; ++e) {
            float ex = __expf(sew[e * NH + h] - m);
            sew[e * NH + h] = ex;
            den += ex;
        }
        float inv = 1.0f / (fmaxf(den, 1e-16f) * (float)NH);
        for (int e = 0; e < d; ++e) sew[e * NH + h] *= inv;
    }
    __syncthreads();

    for (int i = tid; i < d * NH; i += 256) alphaW[(size_t)e0 * NH + i] = sew[i];
}

// ---------------- layer-1: per-head weighted x aggregation -> Z rows ----------------
// Z[n] = [ Z(1024: h*128+f) | x[n](128) | wsum(8) | 0-pad(24) ]  (K=1184)
__global__ __launch_bounds__(256) void z_agg(const f16* __restrict__ X,
                                             const int* __restrict__ offs,
                                             const int* __restrict__ srcCSR,
                                             const float* __restrict__ alphaW,
                                             f16* __restrict__ Z) {
    const int n = blockIdx.x;
    const int e0 = offs[n];
    int d = offs[n + 1] - e0;
    if (d > 256) d = 256;

    __shared__ float sew[256 * NH];
    __shared__ int sed[256];
    __shared__ __align__(16) f16 sx[32 * 128];
    const int tid = threadIdx.x;

    for (int i = tid; i < d * NH; i += 256) sew[i] = alphaW[(size_t)e0 * NH + i];
    for (int e = tid; e < d; e += 256) sed[e] = srcCSR[e0 + e];
    __syncthreads();

    const int h = tid >> 5;              // (tid*4)>>7
    const int f0 = (tid * 4) & 127;
    float a0 = 0.0f, a1 = 0.0f, a2 = 0.0f, a3 = 0.0f;
    for (int ch = 0; ch < d; ch += 32) {
        const int cnt = min(32, d - ch);
        for (int idx = tid; idx < cnt * 16; idx += 256) {
            int row = idx >> 4, c8 = idx & 15;
            *(f16x8*)(sx + row * 128 + c8 * 8) = *(const f16x8*)(X + (size_t)sed[ch + row] * 128 + c8 * 8);
        }
        __syncthreads();
        for (int e = 0; e < cnt; ++e) {
            float w = sew[(ch + e) * NH + h];
            f16x4 xv = *(const f16x4*)(sx + e * 128 + f0);
            a0 += w * (float)xv[0];
            a1 += w * (float)xv[1];
            a2 += w * (float)xv[2];
            a3 += w * (float)xv[3];
        }
        __syncthreads();
    }
    f16* Zr = Z + (size_t)n * 1184;
    f16x4 o; o[0] = (f16)a0; o[1] = (f16)a1; o[2] = (f16)a2; o[3] = (f16)a3;
    *(f16x4*)(Zr + tid * 4) = o;
    if (tid < 16) *(f16x8*)(Zr + 1024 + tid * 8) = *(const f16x8*)(X + (size_t)n * 128 + tid * 8);
    if (tid >= 32 && tid < 40) {
        int hh = tid - 32;
        float s = 0.0f;
        for (int e = 0; e < d; ++e) s += sew[e * NH + hh];
        Zr[1152 + hh] = (f16)s;
    }
    if (tid >= 64 && tid < 88) Zr[1160 + (tid - 64)] = (f16)0.0f;
}

// ---------------- layers 2,3: edge logits + softmax from materialized Q|K ----------
__global__ __launch_bounds__(256) void alpha_fused(const f16* __restrict__ QK,
                                                   const int* __restrict__ offs,
                                                   const int* __restrict__ srcCSR,
                                                   float* __restrict__ alphaW,
                                                   int strideQK, int C, int hc, float scale) {
    const int n = blockIdx.x;
    const int e0 = offs[n];
    int d = offs[n + 1] - e0;
    if (d > 256) d = 256;

    __shared__ __align__(16) f16 sq[4096];
    __shared__ float sew[256 * NH];
    __shared__ int sed[256];
    const int tid = threadIdx.x;

    const f16x8* qg = (const f16x8*)(QK + (size_t)n * strideQK);
    const int qchunks = hc >> 3;
    for (int c = tid; c < qchunks; c += 256) ((f16x8*)sq)[c] = qg[c];
    for (int e = tid; e < d; e += 256) sed[e] = srcCSR[e0 + e];
    __syncthreads();

    const int wv = tid >> 6, lane = tid & 63;
    const int cph = C >> 3;
    const int passes = hc >> 9;
    for (int e = wv; e < d; e += 4) {
        const f16x8* kg = (const f16x8*)(QK + (size_t)sed[e] * strideQK + hc);
        for (int p = 0; p < passes; ++p) {
            const int ci = p * 64 + lane;
            f16x8 qv = ((const f16x8*)sq)[ci];
            f16x8 kv = kg[ci];
            float acc = 0.0f;
#pragma unroll
            for (int t = 0; t < 8; ++t) acc += (float)qv[t] * (float)kv[t];
            for (int o = cph >> 1; o > 0; o >>= 1) acc += __shfl_down(acc, o, cph);
            if ((lane & (cph - 1)) == 0) {
                const int head = ci / cph;
                sew[e * NH + head] = acc * scale;
            }
        }
    }
    __syncthreads();

    if (tid < NH) {
        const int h = tid;
        float m = -3.0e38f;
        for (int e = 0; e < d; ++e) m = fmaxf(m, sew[e * NH + h]);
        float den = 0.0f;
        for (int e = 0; e < d; ++e) {
            float ex = __expf(sew[e * NH + h] - m);
            sew[e * NH + h] = ex;
            den += ex;
        }
        float inv = 1.0f / (fmaxf(den, 1e-16f) * (float)NH);
        for (int e = 0; e < d; ++e) sew[e * NH + h] *= inv;
    }
    __syncthreads();

    for (int i = tid; i < d * NH; i += 256) alphaW[(size_t)e0 * NH + i] = sew[i];
}

// ---------------- per-node: weighted V aggregation + fp32 skip + ELU ----------------
__global__ __launch_bounds__(256) void node_agg(const f16* __restrict__ VS,
                                                const float* __restrict__ Sf,
                                                const int* __restrict__ offs,
                                                const int* __restrict__ srcCSR,
                                                const float* __restrict__ alphaW,
                                                float* __restrict__ hout, f16* __restrict__ houth,
                                                int C, int hc, int NpVS, int writeHout) {
    const int n = blockIdx.x;
    const int e0 = offs[n];
    int d = offs[n + 1] - e0;
    if (d > 256) d = 256;

    __shared__ float sew[256 * NH];
    __shared__ int sed[256];
    __shared__ float sred[512];
    const int tid = threadIdx.x;

    for (int i = tid; i < d * NH; i += 256) sew[i] = alphaW[(size_t)e0 * NH + i];
    for (int e = tid; e < d; e += 256) sed[e] = srcCSR[e0 + e];
    __syncthreads();

    const int half = C >> 1;
    const int cp = tid & (half - 1);
    const int grp = tid / half;
    const int ngr = 256 / half;
    float a0 = 0.0f, a1 = 0.0f;
    for (int e = grp; e < d; e += ngr) {
        const unsigned int* vp = (const unsigned int*)(VS + (size_t)sed[e] * NpVS);
#pragma unroll
        for (int h = 0; h < NH; ++h) {
            float w = sew[e * NH + h];
            f16x2 vv = __builtin_bit_cast(f16x2, vp[((h * C) >> 1) + cp]);
            a0 += w * (float)vv.x;
            a1 += w * (float)vv.y;
        }
    }
    if (ngr > 1) {
        sred[tid] = a0;
        sred[256 + tid] = a1;
        __syncthreads();
        if (grp == 0) {
            for (int g = 1; g < ngr; ++g) {
                a0 += sred[g * half + cp];
                a1 += sred[256 + g * half + cp];
            }
        }
    }
    if (grp == 0) {
        const int c = cp * 2;
        const float* Sp = Sf + (size_t)n * C;
        float o0 = a0 + Sp[c];
        float o1 = a1 + Sp[c + 1];
        o0 = o0 > 0.0f ? o0 : (__expf(o0) - 1.0f);
        o1 = o1 > 0.0f ? o1 : (__expf(o1) - 1.0f);
        if (writeHout) {
            hout[(size_t)n * C + c] = o0;
            hout[(size_t)n * C + c + 1] = o1;
        }
        houth[(size_t)n * C + c] = (f16)o0;
        houth[(size_t)n * C + c + 1] = (f16)o1;
    }
}

// ---------------- fused pooling + final FC: one block per graph, no atomics ----
__global__ __launch_bounds__(256) void pool_graph(const float* __restrict__ h,
                                                  const float* __restrict__ gw, const float* __restrict__ gb,
                                                  const float* __restrict__ fcw, const float* __restrict__ fcb,
                                                  const int* __restrict__ goffs,
                                                  float* __restrict__ gbuf, float* __restrict__ out) {
    const int g = blockIdx.x;
    const int s = goffs[g], e = goffs[g + 1];
    const int tid = threadIdx.x;
    const int wv = tid >> 6, lane = tid & 63;

    __shared__ float red[256];
    __shared__ float pl[64];
    __shared__ float sden;

    if (e == s) {
        if (tid < 10) out[g * 10 + tid] = fcb[tid];
        return;
    }

    const float gwl = gw[lane];
    for (int n = s + wv; n < e; n += 4) {
        float acc = h[(size_t)n * 64 + lane] * gwl;
#pragma unroll
        for (int o = 32; o > 0; o >>= 1) acc += __shfl_down(acc, o, 64);
        if (lane == 0) gbuf[n] = acc + gb[0];
    }
    __syncthreads();

    float m = -3.0e38f;
    for (int n = s + tid; n < e; n += 256) m = fmaxf(m, gbuf[n]);
    red[tid] = m;
    __syncthreads();
    for (int o = 128; o > 0; o >>= 1) {
        if (tid < o) red[tid] = fmaxf(red[tid], red[tid + o]);
        __syncthreads();
    }
    m = red[0];
    __syncthreads();

    float sum = 0.0f;
    for (int n = s + tid; n < e; n += 256) {
        float ex = __expf(gbuf[n] - m);
        gbuf[n] = ex;
        sum += ex;
    }
    red[tid] = sum;
    __syncthreads();
    for (int o = 128; o > 0; o >>= 1) {
        if (tid < o) red[tid] += red[tid + o];
        __syncthreads();
    }
    if (tid == 0) sden = 1.0f / fmaxf(red[0], 1e-16f);
    __syncthreads();

    float acc = 0.0f;
    for (int n = s + wv; n < e; n += 4) acc += gbuf[n] * h[(size_t)n * 64 + lane];
    red[tid] = acc;
    __syncthreads();
    if (wv == 0) pl[lane] = (red[lane] + red[64 + lane] + red[128 + lane] + red[192 + lane]) * sden;
    __syncthreads();

    if (tid < 10) {
        float o = fcb[tid];
#pragma unroll
        for (int c = 0; c < 64; ++c) o += pl[c] * fcw[c * 10 + tid];
        out[g * 10 + tid] = o;
    }
}

// ---------------- host ----------------
extern "C" void kernel_launch(void* const* d_in, const int* in_sizes, int n_in,
                              void* d_out, int out_size, void* d_ws, size_t ws_size,
                              hipStream_t stream) {
    const float* x   = (const float*)d_in[0];
    const int* ei    = (const int*)d_in[1];
    const int* src   = ei;
    const int* dst   = ei + NE;
    const int* batch = (const int*)d_in[2];

    struct LayerW { int fin, C, hc; const float *qw,*qb,*kw,*kb,*vw,*vb,*sw,*sb; };
    LayerW LW[3];
    const int fins[3]   = {128, 512, 256};
    const int Cs[3]     = {512, 256, 64};
    const int NpVS[3]   = {0, 2304, 640};   // V|S widths (layers 2,3 only)
    for (int l = 0; l < 3; ++l) {
        int b = 3 + 8 * l;
        LW[l].fin = fins[l]; LW[l].C = Cs[l]; LW[l].hc = Cs[l] * NH;
        LW[l].qw = (const float*)d_in[b + 0]; LW[l].qb = (const float*)d_in[b + 1];
        LW[l].kw = (const float*)d_in[b + 2]; LW[l].kb = (const float*)d_in[b + 3];
        LW[l].vw = (const float*)d_in[b + 4]; LW[l].vb = (const float*)d_in[b + 5];
        LW[l].sw = (const float*)d_in[b + 6]; LW[l].sb = (const float*)d_in[b + 7];
    }
    const float* gate_w = (const float*)d_in[27];
    const float* gate_b = (const float*)d_in[28];
    const float* fc_w   = (const float*)d_in[29];
    const float* fc_b   = (const float*)d_in[30];

    size_t off = 0;
    char* ws = (char*)d_ws;
    auto alloc = [&](size_t bytes) -> void* {
        void* p = ws + off;
        off = (off + bytes + 255) & ~(size_t)255;
        return p;
    };
    f16* BtQK   = (f16*)alloc((size_t)4096 * 512 * sizeof(f16));
    f16* BtVS   = (f16*)alloc((size_t)2304 * 512 * sizeof(f16));   // also holds 512x1184 Z-B
    float* biasQK = (float*)alloc(8192 * sizeof(float));
    float* biasVS = (float*)alloc(4608 * sizeof(float));
    f16* QKbuf  = (f16*)alloc((size_t)NN * 4608 * sizeof(f16));    // Y / Z / Q|K / V|S per phase
    float* Sf   = (float*)alloc((size_t)NN * 512 * sizeof(float));
    f16* xh     = (f16*)alloc((size_t)NN * 128 * sizeof(f16));
    f16* houth  = (f16*)alloc((size_t)NN * 512 * sizeof(f16));
    float* hf   = (float*)alloc((size_t)NN * 64 * sizeof(float));
    float* alphaW = (float*)alloc((size_t)NE * NH * sizeof(float));
    f16* qw16   = (f16*)alloc((size_t)128 * 4096 * sizeof(f16));
    f16* kw16   = (f16*)alloc((size_t)128 * 4096 * sizeof(f16));
    f16* BtY    = (f16*)alloc((size_t)1152 * 128 * sizeof(f16));
    float* biasY = (float*)alloc(1152 * sizeof(float));
    float* zbias = (float*)alloc(512 * sizeof(float));
    int* deg    = (int*)alloc(NN * sizeof(int));
    int* offs   = (int*)alloc((NN + 1) * sizeof(int));
    int* cursor = (int*)alloc(NN * sizeof(int));
    int* srcCSR = (int*)alloc(NE * sizeof(int));
    int* goffs  = (int*)alloc((NG + 1) * sizeof(int));
    float* gbuf = (float*)alloc(NN * sizeof(float));
    if (off > ws_size) return;

    // CSR build (+ deterministic sort) + graph offsets
    hipMemsetAsync(deg, 0, NN * sizeof(int), stream);
    hipMemsetAsync(zbias, 0, 512 * sizeof(float), stream);
    hipMemsetAsync(biasY, 0, 1152 * sizeof(float), stream);
    hist_kernel<<<(NE + 255) / 256, 256, 0, stream>>>(dst, deg, NE);
    scan_kernel<<<1, 1024, 0, stream>>>(deg, offs, NN);
    copy_int<<<(NN + 255) / 256, 256, 0, stream>>>(offs, cursor, NN);
    scatter_kernel<<<(NE + 255) / 256, 256, 0, stream>>>(src, dst, cursor, srcCSR, NE);
    sort_csr<<<(NN + 255) / 256, 256, 0, stream>>>(offs, srcCSR);
    goffs_kernel<<<1, 64, 0, stream>>>(batch, goffs);

    cvt_f16_kernel<<<(NN * 128 + 255) / 256, 256, 0, stream>>>(x, xh, NN * 128);

    const int grid_m = 80;   // mult of 8: XCD = blockIdx.x % 8 invariant across y-passes
    const f16* Acur = xh;
    for (int l = 0; l < 3; ++l) {
        const int K = LW[l].fin, C = LW[l].C, hc = LW[l].hc;
        const float scale = 1.0f / sqrtf((float)C);

        if (l == 0) {
            // ---- layer 1: Y-trick for alpha, Z-trick for aggregation ----
            const int fin = 128, NtotY = 1152;
            cvt_f16_kernel<<<(fin * hc + 255) / 256, 256, 0, stream>>>(LW[0].qw, qw16, fin * hc);
            cvt_f16_kernel<<<(fin * hc + 255) / 256, 256, 0, stream>>>(LW[0].kw, kw16, fin * hc);
            dim3 gm(1, 1, 8);
            gemm128<<<gm, 256, 0, stream>>>(kw16, hc, C, qw16, hc, C, zbias,
                                            BtY, fin, fin * fin, nullptr, fin, fin, C, 0, 0, 0);
            prepU<<<(fin * 16 + 3) / 4, 256, 0, stream>>>(LW[0].qw, LW[0].qb, LW[0].kw, LW[0].kb,
                                                          BtY, biasY, fin, hc, C);
            dim3 gy(grid_m, NtotY / 128);
            gemm128<<<gy, 256, 0, stream>>>(xh, fin, 0, BtY, fin, 0, biasY,
                                            QKbuf, NtotY, 0, nullptr, NN, NtotY, fin, 0, 0, 0);
            alpha_fused_y<<<NN, 256, 0, stream>>>(QKbuf, xh, offs, srcCSR, alphaW,
                                                  NtotY, fin, scale);
            // Z aggregation (x-row gather, 256B/edge) into QKbuf[NN][1184]
            z_agg<<<NN, 256, 0, stream>>>(xh, offs, srcCSR, alphaW, QKbuf);
            // B = [Wv per-head | Ws | vb], bias = sb; fused ELU epilogue
            prepZB<<<dim3(37, 8), 256, 0, stream>>>(LW[0].vw, LW[0].sw, LW[0].vb, BtVS);
            biasK<<<2, 256, 0, stream>>>(LW[0].sb, 512, LW[0].sb, 0, biasVS, 512);
            dim3 gz(grid_m, 4);
            gemm128<<<gz, 256, 0, stream>>>(QKbuf, 1184, 0, BtVS, 1184, 0, biasVS,
                                            houth, 512, 0, nullptr, NN, 512, 1184, 0, 0, 1);
        } else {
            // ---- layers 2,3: materialized Q|K + V|S path ----
            const int Np0 = 2 * hc, Np1 = NpVS[l];
            prep2t<<<dim3(K / 64, Np0 / 64), 256, 0, stream>>>(LW[l].qw, hc, LW[l].kw, hc,
                                                               BtQK, K, Np0);
            biasK<<<(Np0 + 255) / 256, 256, 0, stream>>>(LW[l].qb, hc, LW[l].kb, hc, biasQK, Np0);
            dim3 gqk(grid_m, Np0 / 128);
            gemm128<<<gqk, 256, 0, stream>>>(Acur, K, 0, BtQK, K, 0, biasQK,
                                             QKbuf, Np0, 0, nullptr, NN, Np0, K, 0, 0, 0);
            alpha_fused<<<NN, 256, 0, stream>>>(QKbuf, offs, srcCSR, alphaW, Np0, C, hc, scale);

            prep2t<<<dim3(K / 64, Np1 / 64), 256, 0, stream>>>(LW[l].vw, hc, LW[l].sw, C,
                                                               BtVS, K, Np1);
            biasK<<<(Np1 + 255) / 256, 256, 0, stream>>>(LW[l].vb, hc, LW[l].sb, C, biasVS, Np1);
            dim3 gvs(grid_m, Np1 / 128);
            gemm128<<<gvs, 256, 0, stream>>>(Acur, K, 0, BtVS, K, 0, biasVS,
                                             QKbuf, Np1, 0, Sf, NN, Np1, K, hc, C, 0);

            node_agg<<<NN, 256, 0, stream>>>(QKbuf, Sf, offs, srcCSR, alphaW, hf, houth,
                                             C, hc, Np1, l == 2 ? 1 : 0);
        }
        Acur = houth;
    }

    pool_graph<<<NG, 256, 0, stream>>>(hf, gate_w, gate_b, fc_w, fc_b, goffs, gbuf, (float*)d_out);
}

// Round 14
// 492.959 us; speedup vs baseline: 1.3514x; 1.1461x over previous
//
#include <hip/hip_runtime.h>
#include <stdint.h>
#include <math.h>

#define NN 10000
#define NE 30000
#define NG 50
#define NH 8

typedef _Float16 f16;
typedef _Float16 f16x2 __attribute__((ext_vector_type(2)));
typedef _Float16 f16x4 __attribute__((ext_vector_type(4)));
typedef _Float16 f16x8 __attribute__((ext_vector_type(8)));
typedef float f32x4 __attribute__((ext_vector_type(4)));

// ---------------- helpers ----------------
__device__ inline void async16(f16* l, const f16* g) {
    __builtin_amdgcn_global_load_lds((const __attribute__((address_space(1))) void*)g,
                                     (__attribute__((address_space(3))) void*)l, 16, 0, 0);
}

// ---------------- CSR build ----------------
__global__ void hist_kernel(const int* __restrict__ dst, int* __restrict__ deg, int E) {
    int e = blockIdx.x * blockDim.x + threadIdx.x;
    if (e < E) atomicAdd(&deg[dst[e]], 1);
}

// block 0: 10-elem/thread scan of deg -> offs[1..NN], cursor[0..NN-1] (=excl prefix)
// block 1: goffs via binary search over sorted batch. ~20 barriers total (old: ~200).
__global__ __launch_bounds__(1024) void scan_goffs(const int* __restrict__ deg, int* __restrict__ offs,
                                                   int* __restrict__ cursor,
                                                   const int* __restrict__ batch, int* __restrict__ goffs) {
    if (blockIdx.x == 1) {
        int g = threadIdx.x;
        if (g > NG) return;
        int lo = 0, hi = NN;
        while (lo < hi) {
            int mid = (lo + hi) >> 1;
            if (batch[mid] < g) lo = mid + 1; else hi = mid;
        }
        goffs[g] = lo;
        return;
    }
    __shared__ int tot[1024];
    const int t = threadIdx.x;
    const int base = t * 10;
    int v[10];
    int s = 0;
#pragma unroll
    for (int i = 0; i < 10; ++i) {
        int idx = base + i;
        v[i] = (idx < NN) ? deg[idx] : 0;
        s += v[i];
    }
    tot[t] = s;
    __syncthreads();
    for (int d2 = 1; d2 < 1024; d2 <<= 1) {
        int add = (t >= d2) ? tot[t - d2] : 0;
        __syncthreads();
        tot[t] += add;
        __syncthreads();
    }
    int run = tot[t] - s;          // exclusive prefix for this thread's chunk
    if (t == 0) offs[0] = 0;
#pragma unroll
    for (int i = 0; i < 10; ++i) {
        int idx = base + i;
        if (idx < NN) cursor[idx] = run;
        run += v[i];
        if (idx < NN) offs[idx + 1] = run;
    }
}

__global__ void scatter_kernel(const int* __restrict__ src, const int* __restrict__ dst,
                               int* __restrict__ cursor, int* __restrict__ srcCSR, int E) {
    int e = blockIdx.x * blockDim.x + threadIdx.x;
    if (e < E) {
        int p = atomicAdd(&cursor[dst[e]], 1);
        srcCSR[p] = src[e];
    }
}

// per-segment insertion sort -> deterministic CSR (fixed fp32 summation orders)
__global__ void sort_csr(const int* __restrict__ offs, int* __restrict__ srcCSR) {
    int n = blockIdx.x * blockDim.x + threadIdx.x;
    if (n >= NN) return;
    int s = offs[n], e = offs[n + 1];
    for (int i = s + 1; i < e; ++i) {
        int v = srcCSR[i];
        int j = i - 1;
        while (j >= s && srcCSR[j] > v) { srcCSR[j + 1] = srcCSR[j]; --j; }
        srcCSR[j + 1] = v;
    }
}

// ---------------- conversions / weight prep ----------------
// three f32->f16 conversions in one dispatch
__global__ void cvt3_kernel(const float* __restrict__ a, f16* __restrict__ ao, int na,
                            const float* __restrict__ b, f16* __restrict__ bo, int nb2,
                            const float* __restrict__ c, f16* __restrict__ co, int nc) {
    int i = blockIdx.x * blockDim.x + threadIdx.x;
    if (i < na) ao[i] = (f16)a[i];
    else if (i < na + nb2) { int j = i - na; bo[j] = (f16)b[j]; }
    else if (i < na + nb2 + nc) { int j = i - na - nb2; co[j] = (f16)c[j]; }
}

// Tiled-transpose 4-way weight prep: Bt[n][k] = f16(W(k,n)), W = [W0|W1|W2|W3|0-pad].
// Bias folded in (blocks with k0==0 write bias[n]).
__global__ __launch_bounds__(256) void prep4t(const float* __restrict__ W0, int n0,
                                              const float* __restrict__ W1, int n1,
                                              const float* __restrict__ W2, int n2,
                                              const float* __restrict__ W3, int n3,
                                              const float* __restrict__ b0, const float* __restrict__ b1,
                                              const float* __restrict__ b2, const float* __restrict__ b3,
                                              f16* __restrict__ Bt, float* __restrict__ bias,
                                              int K, int Ntot) {
    __shared__ float tile[64][65];
    const int k0 = blockIdx.x * 64;
    const int nb = blockIdx.y * 64;
    const int tid = threadIdx.x;
    const int tn = tid & 63;
    const int t4 = tid >> 6;
#pragma unroll
    for (int i = 0; i < 16; ++i) {
        int kl = t4 + i * 4;
        int k = k0 + kl;
        int n = nb + tn;
        float w = 0.0f;
        int m = n;
        if (m < n0) w = W0[(size_t)k * n0 + m];
        else { m -= n0;
            if (m < n1) w = W1[(size_t)k * n1 + m];
            else { m -= n1;
                if (m < n2) w = W2[(size_t)k * n2 + m];
                else { m -= n2; if (m < n3) w = W3[(size_t)k * n3 + m]; }
            }
        }
        tile[kl][tn] = w;
    }
    if (blockIdx.x == 0 && t4 == 0) {
        int n = nb + tn;
        float bv = 0.0f;
        int m = n;
        if (m < n0) bv = b0[m];
        else { m -= n0;
            if (m < n1) bv = b1[m];
            else { m -= n1;
                if (m < n2) bv = b2[m];
                else { m -= n2; if (m < n3) bv = b3[m]; }
            }
        }
        bias[n] = bv;
    }
    __syncthreads();
#pragma unroll
    for (int i = 0; i < 16; ++i) {
        int nl = t4 + i * 4;
        Bt[(size_t)(nb + nl) * K + k0 + tn] = (f16)tile[tn][nl];
    }
}

// u/v rows of the Y transform, one wave per output (k,h,isV)
__global__ __launch_bounds__(256) void prepU(const float* __restrict__ qw, const float* __restrict__ qb,
                                             const float* __restrict__ kw, const float* __restrict__ kb,
                                             f16* __restrict__ BtY, float* __restrict__ biasY,
                                             int fin, int hc, int C) {
    const int wid = blockIdx.x * 4 + ((int)threadIdx.x >> 6);
    const int lane = threadIdx.x & 63;
    if (wid >= fin * 16) return;
    const int k = wid >> 4;
    const int idx = wid & 15;
    const int h = idx & 7, isV = idx >> 3;
    const float* W = isV ? kw : qw;
    const float* bvec = isV ? qb : kb;
    float s = 0.0f;
    for (int c = lane; c < C; c += 64) s += W[(size_t)k * hc + h * C + c] * bvec[h * C + c];
#pragma unroll
    for (int o = 32; o > 0; o >>= 1) s += __shfl_down(s, o, 64);
    if (lane == 0) BtY[(size_t)(8 * fin + isV * 8 + h) * fin + k] = (f16)s;
    if (wid < 8) {
        float cc = 0.0f;
        for (int c = lane; c < C; c += 64) cc += qb[wid * C + c] * kb[wid * C + c];
#pragma unroll
        for (int o = 32; o > 0; o >>= 1) cc += __shfl_down(cc, o, 64);
        if (lane == 0) biasY[8 * fin + wid] = cc;
    }
}

// B for the layer-1 Z-GEMM: Bt2[c][k], K=1184. Bias (sb) folded in.
__global__ __launch_bounds__(256) void prepZB(const float* __restrict__ vw, const float* __restrict__ sw,
                                              const float* __restrict__ vb, const float* __restrict__ sb,
                                              f16* __restrict__ Bt2, float* __restrict__ biasZ) {
    __shared__ f16 tile[32][65];
    const int k0 = blockIdx.x * 32, c0 = blockIdx.y * 64;
    const int tid = threadIdx.x;
#pragma unroll
    for (int i = 0; i < 8; ++i) {
        int idx = tid + i * 256;
        int kl = idx >> 6, cl = idx & 63;
        int k = k0 + kl, c = c0 + cl;
        float v = 0.0f;
        if (k < 1024)      v = vw[(size_t)(k & 127) * 4096 + (k >> 7) * 512 + c];
        else if (k < 1152) v = sw[(size_t)(k - 1024) * 512 + c];
        else if (k < 1160) v = vb[(k - 1152) * 512 + c];
        tile[kl][cl] = (f16)v;
    }
    if (blockIdx.x == 0 && tid < 64) biasZ[c0 + tid] = sb[c0 + tid];
    __syncthreads();
    const int cl = tid >> 2, kl = (tid & 3) * 8;
    f16x8 v;
#pragma unroll
    for (int t = 0; t < 8; ++t) v[t] = tile[kl + t][cl];
    *(f16x8*)(Bt2 + (size_t)(c0 + cl) * 1184 + k0 + kl) = v;
}

// ---------------- gemm128: 128x128 tile, 3-stage ring, vmcnt(4) ----------------
// act!=0 -> fused ELU on output. Sf: cols [hcS, hcS+Sw) also stored fp32.
__global__ __launch_bounds__(256) void gemm128(const f16* __restrict__ A, int lda, int zA,
                                               const f16* __restrict__ Bt, int ldb, int zB,
                                               const float* __restrict__ bias,
                                               f16* __restrict__ C, int ldc, int zC,
                                               float* __restrict__ Sf,
                                               int M, int Np, int K, int hcS, int Sw, int act) {
    __shared__ f16 smem[24576];   // 48 KB = 3 stages x (A 4096 + B 4096 f16)
    const int rm = blockIdx.x * 128;
    if (rm >= M) return;
    A  += (size_t)blockIdx.z * zA;
    Bt += (size_t)blockIdx.z * zB;
    C  += (size_t)blockIdx.z * zC;
    const int tid  = threadIdx.x;
    const int lane = tid & 63;
    const int wave = tid >> 6;
    const int l16  = lane & 15;
    const int quad = lane >> 4;
    const int cn   = blockIdx.y * 128;
    const int wrow = (wave >> 1) * 64;
    const int wcol = (wave & 1) * 64;

    const int rS  = tid >> 2;
    const int kc  = ((tid & 3) ^ ((tid >> 3) & 3)) << 3;
    int rowA0 = rm + rS;       if (rowA0 >= M) rowA0 = M - 1;
    int rowA1 = rm + rS + 64;  if (rowA1 >= M) rowA1 = M - 1;
    const f16* gA0 = A + (size_t)rowA0 * lda + kc;
    const f16* gA1 = A + (size_t)rowA1 * lda + kc;
    const f16* gB0 = Bt + (size_t)(cn + rS) * ldb + kc;
    const f16* gB1 = Bt + (size_t)(cn + rS + 64) * ldb + kc;

    const int swf = (l16 >> 1) & 3;
    const int rdAoff = (wrow + l16) * 32 + ((quad ^ swf) << 3);
    const int rdBoff = 4096 + (wcol + l16) * 32 + ((quad ^ swf) << 3);

    f32x4 acc[4][4] = {};

    auto stage_load = [&](int slot) {
        f16* base = smem + slot * 8192;
        async16(base + tid * 8, gA0);
        async16(base + tid * 8 + 2048, gA1);
        async16(base + 4096 + tid * 8, gB0);
        async16(base + 4096 + tid * 8 + 2048, gB1);
        gA0 += 32; gA1 += 32; gB0 += 32; gB1 += 32;
    };

    const int NI = K >> 5;
    stage_load(0);
    stage_load(1);

    int slot = 0;
    for (int i = 0; i < NI; ++i) {
        if (i + 1 < NI) asm volatile("s_waitcnt vmcnt(4)" ::: "memory");
        else            asm volatile("s_waitcnt vmcnt(0)" ::: "memory");
        asm volatile("s_barrier" ::: "memory");
        if (i + 2 < NI) {
            int s2 = slot + 2; if (s2 >= 3) s2 -= 3;
            stage_load(s2);
        }
        const f16* sb = smem + slot * 8192;
        f16x8 av[4], bv[4];
#pragma unroll
        for (int ii = 0; ii < 4; ++ii) av[ii] = *(const f16x8*)(sb + rdAoff + ii * 512);
#pragma unroll
        for (int j = 0; j < 4; ++j) bv[j] = *(const f16x8*)(sb + rdBoff + j * 512);
#pragma unroll
        for (int ii = 0; ii < 4; ++ii)
#pragma unroll
            for (int j = 0; j < 4; ++j)
                acc[ii][j] = __builtin_amdgcn_mfma_f32_16x16x32_f16(bv[j], av[ii], acc[ii][j], 0, 0, 0);
        ++slot; if (slot == 3) slot = 0;
    }
    __syncthreads();

    f16* sC = smem;    // 64 x 136 f16
    for (int round = 0; round < 2; ++round) {
        if ((wave >> 1) == round) {
#pragma unroll
            for (int j = 0; j < 4; ++j) {
                const int cb = wcol + j * 16 + quad * 4;
                const float4 bb = *(const float4*)(bias + cn + cb);
#pragma unroll
                for (int i = 0; i < 4; ++i) {
                    const int r = i * 16 + l16;
                    float v0 = acc[i][j][0] + bb.x;
                    float v1 = acc[i][j][1] + bb.y;
                    float v2 = acc[i][j][2] + bb.z;
                    float v3 = acc[i][j][3] + bb.w;
                    if (act) {
                        v0 = v0 > 0.0f ? v0 : (__expf(v0) - 1.0f);
                        v1 = v1 > 0.0f ? v1 : (__expf(v1) - 1.0f);
                        v2 = v2 > 0.0f ? v2 : (__expf(v2) - 1.0f);
                        v3 = v3 > 0.0f ? v3 : (__expf(v3) - 1.0f);
                    }
                    f16x4 o;
                    o[0] = (f16)v0; o[1] = (f16)v1; o[2] = (f16)v2; o[3] = (f16)v3;
                    *(f16x4*)(sC + r * 136 + cb) = o;
                    if (Sf) {
                        const int sc = cn + cb - hcS;
                        if (sc >= 0 && sc < Sw) {
                            const int grow = rm + round * 64 + r;
                            if (grow < M) {
                                float4 sv = { v0, v1, v2, v3 };
                                *(float4*)(Sf + (size_t)grow * Sw + sc) = sv;
                            }
                        }
                    }
                }
            }
        }
        __syncthreads();
#pragma unroll
        for (int it = 0; it < 4; ++it) {
            const int r = it * 16 + (tid >> 4);
            const int ch = tid & 15;
            const int grow = rm + round * 64 + r;
            if (grow < M) {
                f16x8 v = *(const f16x8*)(sC + r * 136 + ch * 8);
                *(f16x8*)(C + (size_t)grow * ldc + cn + ch * 8) = v;
            }
        }
        __syncthreads();
    }
}

// ---------------- layer-1 alpha via Y = X@M_h trick ----------------
__global__ __launch_bounds__(256) void alpha_fused_y(const f16* __restrict__ Y, const f16* __restrict__ X,
                                                     const int* __restrict__ offs,
                                                     const int* __restrict__ srcCSR,
                                                     float* __restrict__ alphaW,
                                                     int strideY, int fin, float scale) {
    const int n = blockIdx.x;
    const int e0 = offs[n];
    int d = offs[n + 1] - e0;
    if (d > 256) d = 256;

    __shared__ __align__(16) f16 sy[1024];
    __shared__ float sew[256 * NH];
    __shared__ float sv[256 * NH];
    __shared__ int sed[256];
    __shared__ float su[NH];
    const int tid = threadIdx.x;

    const f16* Yn = Y + (size_t)n * strideY;
    for (int c = tid; c < fin; c += 256) ((f16x8*)sy)[c] = ((const f16x8*)Yn)[c];
    if (tid < NH) su[tid] = (float)Yn[8 * fin + tid];
    for (int e = tid; e < d; e += 256) {
        int s = srcCSR[e0 + e];
        sed[e] = s;
        f16x8 vv = *(const f16x8*)(Y + (size_t)s * strideY + 8 * fin + 8);
#pragma unroll
        for (int t = 0; t < 8; ++t) sv[e * NH + t] = (float)vv[t];
    }
    __syncthreads();

    const int wv = tid >> 6, lane = tid & 63;
    const int cph = fin >> 3;
    const int csh = __ffs(cph) - 1;
    const int passes = fin >> 6;
    for (int e = wv; e < d; e += 4) {
        const f16x8* kg = (const f16x8*)(X + (size_t)sed[e] * fin);
        for (int p = 0; p < passes; ++p) {
            const int ci = p * 64 + lane;
            const int head = ci >> csh;
            const int kcn = ci & (cph - 1);
            f16x8 yv = ((const f16x8*)sy)[ci];
            f16x8 xv = kg[kcn];
            float acc = 0.0f;
#pragma unroll
            for (int t = 0; t < 8; ++t) acc += (float)yv[t] * (float)xv[t];
            for (int o = cph >> 1; o > 0; o >>= 1) acc += __shfl_down(acc, o, cph);
            if ((lane & (cph - 1)) == 0)
                sew[e * NH + head] = (acc + su[head] + sv[e * NH + head]) * scale;
        }
    }
    __syncthreads();

    if (tid < NH) {
        const int h = tid;
        float m = -3.0e38f;
        for (int e = 0; e < d; ++e) m = fmaxf(m, sew[e * NH + h]);
        float den = 0.0f;
        for (int e = 0; e < d; ++e) {
            float ex = __expf(sew[e * NH + h] - m);
            sew[e * NH + h] = ex;
            den += ex;
        }
        float inv = 1.0f / (fmaxf(den, 1e-16f) * (float)NH);
        for (int e = 0; e < d; ++e) sew[e * NH + h] *= inv;
    }
    __syncthreads();

    for (int i = tid; i < d * NH; i += 256) alphaW[(size_t)e0 * NH + i] = sew[i];
}

// ---------------- layer-1: per-head weighted x aggregation -> Z rows ----------------
__global__ __launch_bounds__(256) void z_agg(const f16* __restrict__ X,
                                             const int* __restrict__ offs,
                                             const int* __restrict__ srcCSR,
                                             const float* __restrict__ alphaW,
                                             f16* __restrict__ Z) {
    const int n = blockIdx.x;
    const int e0 = offs[n];
    int d = offs[n + 1] - e0;
    if (d > 256) d = 256;

    __shared__ float sew[256 * NH];
    __shared__ int sed[256];
    __shared__ __align__(16) f16 sx[32 * 128];
    const int tid = threadIdx.x;

    for (int i = tid; i < d * NH; i += 256) sew[i] = alphaW[(size_t)e0 * NH + i];
    for (int e = tid; e < d; e += 256) sed[e] = srcCSR[e0 + e];
    __syncthreads();

    const int h = tid >> 5;
    const int f0 = (tid * 4) & 127;
    float a0 = 0.0f, a1 = 0.0f, a2 = 0.0f, a3 = 0.0f;
    for (int ch = 0; ch < d; ch += 32) {
        const int cnt = min(32, d - ch);
        for (int idx = tid; idx < cnt * 16; idx += 256) {
            int row = idx >> 4, c8 = idx & 15;
            *(f16x8*)(sx + row * 128 + c8 * 8) = *(const f16x8*)(X + (size_t)sed[ch + row] * 128 + c8 * 8);
        }
        __syncthreads();
        for (int e = 0; e < cnt; ++e) {
            float w = sew[(ch + e) * NH + h];
            f16x4 xv = *(const f16x4*)(sx + e * 128 + f0);
            a0 += w * (float)xv[0];
            a1 += w * (float)xv[1];
            a2 += w * (float)xv[2];
            a3 += w * (float)xv[3];
        }
        __syncthreads();
    }
    f16* Zr = Z + (size_t)n * 1184;
    f16x4 o; o[0] = (f16)a0; o[1] = (f16)a1; o[2] = (f16)a2; o[3] = (f16)a3;
    *(f16x4*)(Zr + tid * 4) = o;
    if (tid < 16) *(f16x8*)(Zr + 1024 + tid * 8) = *(const f16x8*)(X + (size_t)n * 128 + tid * 8);
    if (tid >= 32 && tid < 40) {
        int hh = tid - 32;
        float s = 0.0f;
        for (int e = 0; e < d; ++e) s += sew[e * NH + hh];
        Zr[1152 + hh] = (f16)s;
    }
    if (tid >= 64 && tid < 88) Zr[1160 + (tid - 64)] = (f16)0.0f;
}

// ---------------- layers 2,3: edge logits + softmax from materialized Q|K ----------
__global__ __launch_bounds__(256) void alpha_fused(const f16* __restrict__ QK,
                                                   const int* __restrict__ offs,
                                                   const int* __restrict__ srcCSR,
                                                   float* __restrict__ alphaW,
                                                   int strideQK, int C, int hc, float scale) {
    const int n = blockIdx.x;
    const int e0 = offs[n];
    int d = offs[n + 1] - e0;
    if (d > 256) d = 256;

    __shared__ __align__(16) f16 sq[4096];
    __shared__ float sew[256 * NH];
    __shared__ int sed[256];
    const int tid = threadIdx.x;

    const f16x8* qg = (const f16x8*)(QK + (size_t)n * strideQK);
    const int qchunks = hc >> 3;
    for (int c = tid; c < qchunks; c += 256) ((f16x8*)sq)[c] = qg[c];
    for (int e = tid; e < d; e += 256) sed[e] = srcCSR[e0 + e];
    __syncthreads();

    const int wv = tid >> 6, lane = tid & 63;
    const int cph = C >> 3;
    const int passes = hc >> 9;
    for (int e = wv; e < d; e += 4) {
        const f16x8* kg = (const f16x8*)(QK + (size_t)sed[e] * strideQK + hc);
        for (int p = 0; p < passes; ++p) {
            const int ci = p * 64 + lane;
            f16x8 qv = ((const f16x8*)sq)[ci];
            f16x8 kv = kg[ci];
            float acc = 0.0f;
#pragma unroll
            for (int t = 0; t < 8; ++t) acc += (float)qv[t] * (float)kv[t];
            for (int o = cph >> 1; o > 0; o >>= 1) acc += __shfl_down(acc, o, cph);
            if ((lane & (cph - 1)) == 0) {
                const int head = ci / cph;
                sew[e * NH + head] = acc * scale;
            }
        }
    }
    __syncthreads();

    if (tid < NH) {
        const int h = tid;
        float m = -3.0e38f;
        for (int e = 0; e < d; ++e) m = fmaxf(m, sew[e * NH + h]);
        float den = 0.0f;
        for (int e = 0; e < d; ++e) {
            float ex = __expf(sew[e * NH + h] - m);
            sew[e * NH + h] = ex;
            den += ex;
        }
        float inv = 1.0f / (fmaxf(den, 1e-16f) * (float)NH);
        for (int e = 0; e < d; ++e) sew[e * NH + h] *= inv;
    }
    __syncthreads();

    for (int i = tid; i < d * NH; i += 256) alphaW[(size_t)e0 * NH + i] = sew[i];
}

// ---------------- per-node: weighted V aggregation + fp32 skip + ELU ----------------
__global__ __launch_bounds__(256) void node_agg(const f16* __restrict__ VS,
                                                const float* __restrict__ Sf,
                                                const int* __restrict__ offs,
                                                const int* __restrict__ srcCSR,
                                                const float* __restrict__ alphaW,
                                                float* __restrict__ hout, f16* __restrict__ houth,
                                                int C, int NpVS, int writeHout) {
    const int n = blockIdx.x;
    const int e0 = offs[n];
    int d = offs[n + 1] - e0;
    if (d > 256) d = 256;

    __shared__ float sew[256 * NH];
    __shared__ int sed[256];
    __shared__ float sred[512];
    const int tid = threadIdx.x;

    for (int i = tid; i < d * NH; i += 256) sew[i] = alphaW[(size_t)e0 * NH + i];
    for (int e = tid; e < d; e += 256) sed[e] = srcCSR[e0 + e];
    __syncthreads();

    const int half = C >> 1;
    const int cp = tid & (half - 1);
    const int grp = tid / half;
    const int ngr = 256 / half;
    float a0 = 0.0f, a1 = 0.0f;
    for (int e = grp; e < d; e += ngr) {
        const unsigned int* vp = (const unsigned int*)(VS + (size_t)sed[e] * NpVS);
#pragma unroll
        for (int h = 0; h < NH; ++h) {
            float w = sew[e * NH + h];
            f16x2 vv = __builtin_bit_cast(f16x2, vp[((h * C) >> 1) + cp]);
            a0 += w * (float)vv.x;
            a1 += w * (float)vv.y;
        }
    }
    if (ngr > 1) {
        sred[tid] = a0;
        sred[256 + tid] = a1;
        __syncthreads();
        if (grp == 0) {
            for (int g = 1; g < ngr; ++g) {
                a0 += sred[g * half + cp];
                a1 += sred[256 + g * half + cp];
            }
        }
    }
    if (grp == 0) {
        const int c = cp * 2;
        const float* Sp = Sf + (size_t)n * C;
        float o0 = a0 + Sp[c];
        float o1 = a1 + Sp[c + 1];
        o0 = o0 > 0.0f ? o0 : (__expf(o0) - 1.0f);
        o1 = o1 > 0.0f ? o1 : (__expf(o1) - 1.0f);
        if (writeHout) {
            hout[(size_t)n * C + c] = o0;
            hout[(size_t)n * C + c + 1] = o1;
        }
        houth[(size_t)n * C + c] = (f16)o0;
        houth[(size_t)n * C + c + 1] = (f16)o1;
    }
}

// ---------------- fused pooling + final FC: one block per graph, no atomics ----
__global__ __launch_bounds__(256) void pool_graph(const float* __restrict__ h,
                                                  const float* __restrict__ gw, const float* __restrict__ gb,
                                                  const float* __restrict__ fcw, const float* __restrict__ fcb,
                                                  const int* __restrict__ goffs,
                                                  float* __restrict__ gbuf, float* __restrict__ out) {
    const int g = blockIdx.x;
    const int s = goffs[g], e = goffs[g + 1];
    const int tid = threadIdx.x;
    const int wv = tid >> 6, lane = tid & 63;

    __shared__ float red[256];
    __shared__ float pl[64];
    __shared__ float sden;

    if (e == s) {
        if (tid < 10) out[g * 10 + tid] = fcb[tid];
        return;
    }

    const float gwl = gw[lane];
    for (int n = s + wv; n < e; n += 4) {
        float acc = h[(size_t)n * 64 + lane] * gwl;
#pragma unroll
        for (int o = 32; o > 0; o >>= 1) acc += __shfl_down(acc, o, 64);
        if (lane == 0) gbuf[n] = acc + gb[0];
    }
    __syncthreads();

    float m = -3.0e38f;
    for (int n = s + tid; n < e; n += 256) m = fmaxf(m, gbuf[n]);
    red[tid] = m;
    __syncthreads();
    for (int o = 128; o > 0; o >>= 1) {
        if (tid < o) red[tid] = fmaxf(red[tid], red[tid + o]);
        __syncthreads();
    }
    m = red[0];
    __syncthreads();

    float sum = 0.0f;
    for (int n = s + tid; n < e; n += 256) {
        float ex = __expf(gbuf[n] - m);
        gbuf[n] = ex;
        sum += ex;
    }
    red[tid] = sum;
    __syncthreads();
    for (int o = 128; o > 0; o >>= 1) {
        if (tid < o) red[tid] += red[tid + o];
        __syncthreads();
    }
    if (tid == 0) sden = 1.0f / fmaxf(red[0], 1e-16f);
    __syncthreads();

    float acc = 0.0f;
    for (int n = s + wv; n < e; n += 4) acc += gbuf[n] * h[(size_t)n * 64 + lane];
    red[tid] = acc;
    __syncthreads();
    if (wv == 0) pl[lane] = (red[lane] + red[64 + lane] + red[128 + lane] + red[192 + lane]) * sden;
    __syncthreads();

    if (tid < 10) {
        float o = fcb[tid];
#pragma unroll
        for (int c = 0; c < 64; ++c) o += pl[c] * fcw[c * 10 + tid];
        out[g * 10 + tid] = o;
    }
}

// ---------------- host ----------------
extern "C" void kernel_launch(void* const* d_in, const int* in_sizes, int n_in,
                              void* d_out, int out_size, void* d_ws, size_t ws_size,
                              hipStream_t stream) {
    const float* x   = (const float*)d_in[0];
    const int* ei    = (const int*)d_in[1];
    const int* src   = ei;
    const int* dst   = ei + NE;
    const int* batch = (const int*)d_in[2];

    struct LayerW { int fin, C, hc; const float *qw,*qb,*kw,*kb,*vw,*vb,*sw,*sb; };
    LayerW LW[3];
    const int fins[3] = {128, 512, 256};
    const int Cs[3]   = {512, 256, 64};
    for (int l = 0; l < 3; ++l) {
        int b = 3 + 8 * l;
        LW[l].fin = fins[l]; LW[l].C = Cs[l]; LW[l].hc = Cs[l] * NH;
        LW[l].qw = (const float*)d_in[b + 0]; LW[l].qb = (const float*)d_in[b + 1];
        LW[l].kw = (const float*)d_in[b + 2]; LW[l].kb = (const float*)d_in[b + 3];
        LW[l].vw = (const float*)d_in[b + 4]; LW[l].vb = (const float*)d_in[b + 5];
        LW[l].sw = (const float*)d_in[b + 6]; LW[l].sb = (const float*)d_in[b + 7];
    }
    const float* gate_w = (const float*)d_in[27];
    const float* gate_b = (const float*)d_in[28];
    const float* fc_w   = (const float*)d_in[29];
    const float* fc_b   = (const float*)d_in[30];

    size_t off = 0;
    char* ws = (char*)d_ws;
    auto alloc = [&](size_t bytes) -> void* {
        void* p = ws + off;
        off = (off + bytes + 255) & ~(size_t)255;
        return p;
    };
    f16* BtQK   = (f16*)alloc((size_t)6400 * 512 * sizeof(f16));   // fused Q|K|V|S weights
    f16* BtVS   = (f16*)alloc((size_t)512 * 1184 * sizeof(f16));   // layer-1 Z-B
    float* biasQK = (float*)alloc(6400 * sizeof(float));
    float* biasVS = (float*)alloc(512 * sizeof(float));
    f16* QKbuf  = (f16*)alloc((size_t)NN * 6400 * sizeof(f16));    // Y / Z / Q|K|V|S per phase
    float* Sf   = (float*)alloc((size_t)NN * 256 * sizeof(float)); // fp32 skip (layers 2,3)
    f16* xh     = (f16*)alloc((size_t)NN * 128 * sizeof(f16));
    f16* houth  = (f16*)alloc((size_t)NN * 512 * sizeof(f16));
    float* hf   = (float*)alloc((size_t)NN * 64 * sizeof(float));
    float* alphaW = (float*)alloc((size_t)NE * NH * sizeof(float));
    f16* qw16   = (f16*)alloc((size_t)128 * 4096 * sizeof(f16));
    f16* kw16   = (f16*)alloc((size_t)128 * 4096 * sizeof(f16));
    f16* BtY    = (f16*)alloc((size_t)1152 * 128 * sizeof(f16));
    // contiguous zero-init region: deg | zbias | biasY (single memset)
    int*   deg   = (int*)alloc(NN * sizeof(int));
    float* zbias = (float*)alloc(512 * sizeof(float));
    float* biasY = (float*)alloc(1152 * sizeof(float));
    size_t zspan = (size_t)((char*)(biasY + 1152) - (char*)deg);
    int* offs   = (int*)alloc((NN + 1) * sizeof(int));
    int* cursor = (int*)alloc(NN * sizeof(int));
    int* srcCSR = (int*)alloc(NE * sizeof(int));
    int* goffs  = (int*)alloc((NG + 1) * sizeof(int));
    float* gbuf = (float*)alloc(NN * sizeof(float));
    if (off > ws_size) return;

    hipMemsetAsync(deg, 0, zspan, stream);
    hist_kernel<<<(NE + 255) / 256, 256, 0, stream>>>(dst, deg, NE);
    scan_goffs<<<2, 1024, 0, stream>>>(deg, offs, cursor, batch, goffs);
    scatter_kernel<<<(NE + 255) / 256, 256, 0, stream>>>(src, dst, cursor, srcCSR, NE);
    sort_csr<<<(NN + 255) / 256, 256, 0, stream>>>(offs, srcCSR);

    // x->xh, qw1->qw16, kw1->kw16 in one dispatch
    {
        int na = NN * 128, nb2 = 128 * 4096, nc = 128 * 4096;
        cvt3_kernel<<<(na + nb2 + nc + 255) / 256, 256, 0, stream>>>(x, xh, na,
                                                                     LW[0].qw, qw16, nb2,
                                                                     LW[0].kw, kw16, nc);
    }

    const int grid_m = 80;   // mult of 8: XCD = blockIdx.x % 8 invariant across y-passes
    const f16* Acur = xh;
    for (int l = 0; l < 3; ++l) {
        const int K = LW[l].fin, C = LW[l].C, hc = LW[l].hc;
        const float scale = 1.0f / sqrtf((float)C);

        if (l == 0) {
            // ---- layer 1: Y-trick for alpha, Z-trick for aggregation ----
            const int fin = 128, NtotY = 1152;
            dim3 gm(1, 1, 8);
            gemm128<<<gm, 256, 0, stream>>>(kw16, hc, C, qw16, hc, C, zbias,
                                            BtY, fin, fin * fin, nullptr, fin, fin, C, 0, 0, 0);
            prepU<<<(fin * 16 + 3) / 4, 256, 0, stream>>>(LW[0].qw, LW[0].qb, LW[0].kw, LW[0].kb,
                                                          BtY, biasY, fin, hc, C);
            dim3 gy(grid_m, NtotY / 128);
            gemm128<<<gy, 256, 0, stream>>>(xh, fin, 0, BtY, fin, 0, biasY,
                                            QKbuf, NtotY, 0, nullptr, NN, NtotY, fin, 0, 0, 0);
            alpha_fused_y<<<NN, 256, 0, stream>>>(QKbuf, xh, offs, srcCSR, alphaW,
                                                  NtotY, fin, scale);
            z_agg<<<NN, 256, 0, stream>>>(xh, offs, srcCSR, alphaW, QKbuf);
            prepZB<<<dim3(37, 8), 256, 0, stream>>>(LW[0].vw, LW[0].sw, LW[0].vb, LW[0].sb,
                                                    BtVS, biasVS);
            dim3 gz(grid_m, 4);
            gemm128<<<gz, 256, 0, stream>>>(QKbuf, 1184, 0, BtVS, 1184, 0, biasVS,
                                            houth, 512, 0, nullptr, NN, 512, 1184, 0, 0, 1);
        } else {
            // ---- layers 2,3: ONE fused Q|K|V|S GEMM, then alpha, then node_agg ----
            const int Np = (2 * hc + hc + C + 127) & ~127;   // L2: 6400, L3: 1664
            prep4t<<<dim3(K / 64, Np / 64), 256, 0, stream>>>(LW[l].qw, hc, LW[l].kw, hc,
                                                              LW[l].vw, hc, LW[l].sw, C,
                                                              LW[l].qb, LW[l].kb, LW[l].vb, LW[l].sb,
                                                              BtQK, biasQK, K, Np);
            dim3 gq(grid_m, Np / 128);
            gemm128<<<gq, 256, 0, stream>>>(Acur, K, 0, BtQK, K, 0, biasQK,
                                            QKbuf, Np, 0, Sf, NN, Np, K, 3 * hc, C, 0);
            alpha_fused<<<NN, 256, 0, stream>>>(QKbuf, offs, srcCSR, alphaW, Np, C, hc, scale);
            node_agg<<<NN, 256, 0, stream>>>(QKbuf + 2 * hc, Sf, offs, srcCSR, alphaW, hf, houth,
                                             C, Np, l == 2 ? 1 : 0);
        }
        Acur = houth;
    }

    pool_graph<<<NG, 256, 0, stream>>>(hf, gate_w, gate_b, fc_w, fc_b, goffs, gbuf, (float*)d_out);
}

// Round 15
// 475.395 us; speedup vs baseline: 1.4013x; 1.0369x over previous
//
#include <hip/hip_runtime.h>
#include <stdint.h>
#include <math.h>

#define NN 10000
#define NE 30000
#define NG 50
#define NH 8

typedef _Float16 f16;
typedef _Float16 f16x2 __attribute__((ext_vector_type(2)));
typedef _Float16 f16x4 __attribute__((ext_vector_type(4)));
typedef _Float16 f16x8 __attribute__((ext_vector_type(8)));
typedef float f32x4 __attribute__((ext_vector_type(4)));

// ---------------- helpers ----------------
__device__ inline void async16(f16* l, const f16* g) {
    __builtin_amdgcn_global_load_lds((const __attribute__((address_space(1))) void*)g,
                                     (__attribute__((address_space(3))) void*)l, 16, 0, 0);
}

// ---------------- CSR build ----------------
__global__ void hist_kernel(const int* __restrict__ dst, int* __restrict__ deg, int E) {
    int e = blockIdx.x * blockDim.x + threadIdx.x;
    if (e < E) atomicAdd(&deg[dst[e]], 1);
}

__global__ __launch_bounds__(1024) void scan_goffs(const int* __restrict__ deg, int* __restrict__ offs,
                                                   int* __restrict__ cursor,
                                                   const int* __restrict__ batch, int* __restrict__ goffs) {
    if (blockIdx.x == 1) {
        int g = threadIdx.x;
        if (g > NG) return;
        int lo = 0, hi = NN;
        while (lo < hi) {
            int mid = (lo + hi) >> 1;
            if (batch[mid] < g) lo = mid + 1; else hi = mid;
        }
        goffs[g] = lo;
        return;
    }
    __shared__ int tot[1024];
    const int t = threadIdx.x;
    const int base = t * 10;
    int v[10];
    int s = 0;
#pragma unroll
    for (int i = 0; i < 10; ++i) {
        int idx = base + i;
        v[i] = (idx < NN) ? deg[idx] : 0;
        s += v[i];
    }
    tot[t] = s;
    __syncthreads();
    for (int d2 = 1; d2 < 1024; d2 <<= 1) {
        int add = (t >= d2) ? tot[t - d2] : 0;
        __syncthreads();
        tot[t] += add;
        __syncthreads();
    }
    int run = tot[t] - s;
    if (t == 0) offs[0] = 0;
#pragma unroll
    for (int i = 0; i < 10; ++i) {
        int idx = base + i;
        if (idx < NN) cursor[idx] = run;
        run += v[i];
        if (idx < NN) offs[idx + 1] = run;
    }
}

__global__ void scatter_kernel(const int* __restrict__ src, const int* __restrict__ dst,
                               int* __restrict__ cursor, int* __restrict__ srcCSR, int E) {
    int e = blockIdx.x * blockDim.x + threadIdx.x;
    if (e < E) {
        int p = atomicAdd(&cursor[dst[e]], 1);
        srcCSR[p] = src[e];
    }
}

__global__ void sort_csr(const int* __restrict__ offs, int* __restrict__ srcCSR) {
    int n = blockIdx.x * blockDim.x + threadIdx.x;
    if (n >= NN) return;
    int s = offs[n], e = offs[n + 1];
    for (int i = s + 1; i < e; ++i) {
        int v = srcCSR[i];
        int j = i - 1;
        while (j >= s && srcCSR[j] > v) { srcCSR[j + 1] = srcCSR[j]; --j; }
        srcCSR[j + 1] = v;
    }
}

// ---------------- conversions / weight prep ----------------
__global__ void cvt3_kernel(const float* __restrict__ a, f16* __restrict__ ao, int na,
                            const float* __restrict__ b, f16* __restrict__ bo, int nb2,
                            const float* __restrict__ c, f16* __restrict__ co, int nc) {
    int i = blockIdx.x * blockDim.x + threadIdx.x;
    if (i < na) ao[i] = (f16)a[i];
    else if (i < na + nb2) { int j = i - na; bo[j] = (f16)b[j]; }
    else if (i < na + nb2 + nc) { int j = i - na - nb2; co[j] = (f16)c[j]; }
}

// Two-layer 4-way tiled-transpose weight prep in ONE dispatch (blockIdx.z selects layer).
__global__ __launch_bounds__(256) void prep4t2(
        const float* W0a, int n0a, const float* W1a, int n1a,
        const float* W2a, int n2a, const float* W3a, int n3a,
        const float* b0a, const float* b1a, const float* b2a, const float* b3a,
        f16* Bta, float* biasa, int Ka, int Na,
        const float* W0b, int n0b, const float* W1b, int n1b,
        const float* W2b, int n2b, const float* W3b, int n3b,
        const float* b0b, const float* b1b, const float* b2b, const float* b3b,
        f16* Btb, float* biasb, int Kb, int Nb) {
    const int z = blockIdx.z;
    const float *W0 = z ? W0b : W0a, *W1 = z ? W1b : W1a, *W2 = z ? W2b : W2a, *W3 = z ? W3b : W3a;
    const float *b0 = z ? b0b : b0a, *b1 = z ? b1b : b1a, *b2 = z ? b2b : b2a, *b3 = z ? b3b : b3a;
    const int n0 = z ? n0b : n0a, n1 = z ? n1b : n1a, n2 = z ? n2b : n2a, n3 = z ? n3b : n3a;
    const int K = z ? Kb : Ka, Ntot = z ? Nb : Na;
    f16* Bt = z ? Btb : Bta;
    float* bias = z ? biasb : biasa;
    if ((int)blockIdx.x * 64 >= K || (int)blockIdx.y * 64 >= Ntot) return;

    __shared__ float tile[64][65];
    const int k0 = blockIdx.x * 64;
    const int nb = blockIdx.y * 64;
    const int tid = threadIdx.x;
    const int tn = tid & 63;
    const int t4 = tid >> 6;
#pragma unroll
    for (int i = 0; i < 16; ++i) {
        int kl = t4 + i * 4;
        int k = k0 + kl;
        int n = nb + tn;
        float w = 0.0f;
        int m = n;
        if (m < n0) w = W0[(size_t)k * n0 + m];
        else { m -= n0;
            if (m < n1) w = W1[(size_t)k * n1 + m];
            else { m -= n1;
                if (m < n2) w = W2[(size_t)k * n2 + m];
                else { m -= n2; if (m < n3) w = W3[(size_t)k * n3 + m]; }
            }
        }
        tile[kl][tn] = w;
    }
    if (blockIdx.x == 0 && t4 == 0) {
        int n = nb + tn;
        float bv = 0.0f;
        int m = n;
        if (m < n0) bv = b0[m];
        else { m -= n0;
            if (m < n1) bv = b1[m];
            else { m -= n1;
                if (m < n2) bv = b2[m];
                else { m -= n2; if (m < n3) bv = b3[m]; }
            }
        }
        bias[n] = bv;
    }
    __syncthreads();
#pragma unroll
    for (int i = 0; i < 16; ++i) {
        int nl = t4 + i * 4;
        Bt[(size_t)(nb + nl) * K + k0 + tn] = (f16)tile[tn][nl];
    }
}

// u/v rows of the Y transform, one wave per output (k,h,isV)
__global__ __launch_bounds__(256) void prepU(const float* __restrict__ qw, const float* __restrict__ qb,
                                             const float* __restrict__ kw, const float* __restrict__ kb,
                                             f16* __restrict__ BtY, float* __restrict__ biasY,
                                             int fin, int hc, int C) {
    const int wid = blockIdx.x * 4 + ((int)threadIdx.x >> 6);
    const int lane = threadIdx.x & 63;
    if (wid >= fin * 16) return;
    const int k = wid >> 4;
    const int idx = wid & 15;
    const int h = idx & 7, isV = idx >> 3;
    const float* W = isV ? kw : qw;
    const float* bvec = isV ? qb : kb;
    float s = 0.0f;
    for (int c = lane; c < C; c += 64) s += W[(size_t)k * hc + h * C + c] * bvec[h * C + c];
#pragma unroll
    for (int o = 32; o > 0; o >>= 1) s += __shfl_down(s, o, 64);
    if (lane == 0) BtY[(size_t)(8 * fin + isV * 8 + h) * fin + k] = (f16)s;
    if (wid < 8) {
        float cc = 0.0f;
        for (int c = lane; c < C; c += 64) cc += qb[wid * C + c] * kb[wid * C + c];
#pragma unroll
        for (int o = 32; o > 0; o >>= 1) cc += __shfl_down(cc, o, 64);
        if (lane == 0) biasY[8 * fin + wid] = cc;
    }
}

// B for the layer-1 Z-GEMM: Bt2[c][k], K=1184. Bias (sb) folded in.
__global__ __launch_bounds__(256) void prepZB(const float* __restrict__ vw, const float* __restrict__ sw,
                                              const float* __restrict__ vb, const float* __restrict__ sb,
                                              f16* __restrict__ Bt2, float* __restrict__ biasZ) {
    __shared__ f16 tile[32][65];
    const int k0 = blockIdx.x * 32, c0 = blockIdx.y * 64;
    const int tid = threadIdx.x;
#pragma unroll
    for (int i = 0; i < 8; ++i) {
        int idx = tid + i * 256;
        int kl = idx >> 6, cl = idx & 63;
        int k = k0 + kl, c = c0 + cl;
        float v = 0.0f;
        if (k < 1024)      v = vw[(size_t)(k & 127) * 4096 + (k >> 7) * 512 + c];
        else if (k < 1152) v = sw[(size_t)(k - 1024) * 512 + c];
        else if (k < 1160) v = vb[(k - 1152) * 512 + c];
        tile[kl][cl] = (f16)v;
    }
    if (blockIdx.x == 0 && tid < 64) biasZ[c0 + tid] = sb[c0 + tid];
    __syncthreads();
    const int cl = tid >> 2, kl = (tid & 3) * 8;
    f16x8 v;
#pragma unroll
    for (int t = 0; t < 8; ++t) v[t] = tile[kl + t][cl];
    *(f16x8*)(Bt2 + (size_t)(c0 + cl) * 1184 + k0 + kl) = v;
}

// ---------------- gemm128: 128x128 tile, 3-stage ring, vmcnt(4) ----------------
__global__ __launch_bounds__(256) void gemm128(const f16* __restrict__ A, int lda, int zA,
                                               const f16* __restrict__ Bt, int ldb, int zB,
                                               const float* __restrict__ bias,
                                               f16* __restrict__ C, int ldc, int zC,
                                               float* __restrict__ Sf,
                                               int M, int Np, int K, int hcS, int Sw, int act) {
    __shared__ f16 smem[24576];
    const int rm = blockIdx.x * 128;
    if (rm >= M) return;
    A  += (size_t)blockIdx.z * zA;
    Bt += (size_t)blockIdx.z * zB;
    C  += (size_t)blockIdx.z * zC;
    const int tid  = threadIdx.x;
    const int lane = tid & 63;
    const int wave = tid >> 6;
    const int l16  = lane & 15;
    const int quad = lane >> 4;
    const int cn   = blockIdx.y * 128;
    const int wrow = (wave >> 1) * 64;
    const int wcol = (wave & 1) * 64;

    const int rS  = tid >> 2;
    const int kc  = ((tid & 3) ^ ((tid >> 3) & 3)) << 3;
    int rowA0 = rm + rS;       if (rowA0 >= M) rowA0 = M - 1;
    int rowA1 = rm + rS + 64;  if (rowA1 >= M) rowA1 = M - 1;
    const f16* gA0 = A + (size_t)rowA0 * lda + kc;
    const f16* gA1 = A + (size_t)rowA1 * lda + kc;
    const f16* gB0 = Bt + (size_t)(cn + rS) * ldb + kc;
    const f16* gB1 = Bt + (size_t)(cn + rS + 64) * ldb + kc;

    const int swf = (l16 >> 1) & 3;
    const int rdAoff = (wrow + l16) * 32 + ((quad ^ swf) << 3);
    const int rdBoff = 4096 + (wcol + l16) * 32 + ((quad ^ swf) << 3);

    f32x4 acc[4][4] = {};

    auto stage_load = [&](int slot) {
        f16* base = smem + slot * 8192;
        async16(base + tid * 8, gA0);
        async16(base + tid * 8 + 2048, gA1);
        async16(base + 4096 + tid * 8, gB0);
        async16(base + 4096 + tid * 8 + 2048, gB1);
        gA0 += 32; gA1 += 32; gB0 += 32; gB1 += 32;
    };

    const int NI = K >> 5;
    stage_load(0);
    stage_load(1);

    int slot = 0;
    for (int i = 0; i < NI; ++i) {
        if (i + 1 < NI) asm volatile("s_waitcnt vmcnt(4)" ::: "memory");
        else            asm volatile("s_waitcnt vmcnt(0)" ::: "memory");
        asm volatile("s_barrier" ::: "memory");
        if (i + 2 < NI) {
            int s2 = slot + 2; if (s2 >= 3) s2 -= 3;
            stage_load(s2);
        }
        const f16* sb = smem + slot * 8192;
        f16x8 av[4], bv[4];
#pragma unroll
        for (int ii = 0; ii < 4; ++ii) av[ii] = *(const f16x8*)(sb + rdAoff + ii * 512);
#pragma unroll
        for (int j = 0; j < 4; ++j) bv[j] = *(const f16x8*)(sb + rdBoff + j * 512);
#pragma unroll
        for (int ii = 0; ii < 4; ++ii)
#pragma unroll
            for (int j = 0; j < 4; ++j)
                acc[ii][j] = __builtin_amdgcn_mfma_f32_16x16x32_f16(bv[j], av[ii], acc[ii][j], 0, 0, 0);
        ++slot; if (slot == 3) slot = 0;
    }
    __syncthreads();

    f16* sC = smem;
    for (int round = 0; round < 2; ++round) {
        if ((wave >> 1) == round) {
#pragma unroll
            for (int j = 0; j < 4; ++j) {
                const int cb = wcol + j * 16 + quad * 4;
                const float4 bb = *(const float4*)(bias + cn + cb);
#pragma unroll
                for (int i = 0; i < 4; ++i) {
                    const int r = i * 16 + l16;
                    float v0 = acc[i][j][0] + bb.x;
                    float v1 = acc[i][j][1] + bb.y;
                    float v2 = acc[i][j][2] + bb.z;
                    float v3 = acc[i][j][3] + bb.w;
                    if (act) {
                        v0 = v0 > 0.0f ? v0 : (__expf(v0) - 1.0f);
                        v1 = v1 > 0.0f ? v1 : (__expf(v1) - 1.0f);
                        v2 = v2 > 0.0f ? v2 : (__expf(v2) - 1.0f);
                        v3 = v3 > 0.0f ? v3 : (__expf(v3) - 1.0f);
                    }
                    f16x4 o;
                    o[0] = (f16)v0; o[1] = (f16)v1; o[2] = (f16)v2; o[3] = (f16)v3;
                    *(f16x4*)(sC + r * 136 + cb) = o;
                    if (Sf) {
                        const int sc = cn + cb - hcS;
                        if (sc >= 0 && sc < Sw) {
                            const int grow = rm + round * 64 + r;
                            if (grow < M) {
                                float4 sv = { v0, v1, v2, v3 };
                                *(float4*)(Sf + (size_t)grow * Sw + sc) = sv;
                            }
                        }
                    }
                }
            }
        }
        __syncthreads();
#pragma unroll
        for (int it = 0; it < 4; ++it) {
            const int r = it * 16 + (tid >> 4);
            const int ch = tid & 15;
            const int grow = rm + round * 64 + r;
            if (grow < M) {
                f16x8 v = *(const f16x8*)(sC + r * 136 + ch * 8);
                *(f16x8*)(C + (size_t)grow * ldc + cn + ch * 8) = v;
            }
        }
        __syncthreads();
    }
}

// ---------------- layer-1: alpha (Y-trick) + softmax + Z aggregation, fused ----------
__global__ __launch_bounds__(256) void alpha_zagg(const f16* __restrict__ Y, const f16* __restrict__ X,
                                                  const int* __restrict__ offs,
                                                  const int* __restrict__ srcCSR,
                                                  f16* __restrict__ Z,
                                                  int strideY, float scale) {
    const int fin = 128;
    const int n = blockIdx.x;
    const int e0 = offs[n];
    int d = offs[n + 1] - e0;
    if (d > 256) d = 256;

    __shared__ __align__(16) f16 sy[1024];
    __shared__ float sew[256 * NH];
    __shared__ float sv[256 * NH];
    __shared__ int sed[256];
    __shared__ float su[NH];
    __shared__ __align__(16) f16 sx[32 * 128];
    const int tid = threadIdx.x;

    const f16* Yn = Y + (size_t)n * strideY;
    for (int c = tid; c < fin; c += 256) ((f16x8*)sy)[c] = ((const f16x8*)Yn)[c];
    if (tid < NH) su[tid] = (float)Yn[8 * fin + tid];
    for (int e = tid; e < d; e += 256) {
        int s = srcCSR[e0 + e];
        sed[e] = s;
        f16x8 vv = *(const f16x8*)(Y + (size_t)s * strideY + 8 * fin + 8);
#pragma unroll
        for (int t = 0; t < 8; ++t) sv[e * NH + t] = (float)vv[t];
    }
    __syncthreads();

    {
        const int wv = tid >> 6, lane = tid & 63;
        for (int e = wv; e < d; e += 4) {
            const f16x8* kg = (const f16x8*)(X + (size_t)sed[e] * fin);
#pragma unroll
            for (int p = 0; p < 2; ++p) {
                const int ci = p * 64 + lane;
                const int head = ci >> 4;
                const int kcn = ci & 15;
                f16x8 yv = ((const f16x8*)sy)[ci];
                f16x8 xv = kg[kcn];
                float acc = 0.0f;
#pragma unroll
                for (int t = 0; t < 8; ++t) acc += (float)yv[t] * (float)xv[t];
#pragma unroll
                for (int o = 8; o > 0; o >>= 1) acc += __shfl_down(acc, o, 16);
                if ((lane & 15) == 0)
                    sew[e * NH + head] = (acc + su[head] + sv[e * NH + head]) * scale;
            }
        }
    }
    __syncthreads();

    if (tid < NH) {
        const int h = tid;
        float m = -3.0e38f;
        for (int e = 0; e < d; ++e) m = fmaxf(m, sew[e * NH + h]);
        float den = 0.0f;
        for (int e = 0; e < d; ++e) {
            float ex = __expf(sew[e * NH + h] - m);
            sew[e * NH + h] = ex;
            den += ex;
        }
        float inv = 1.0f / (fmaxf(den, 1e-16f) * (float)NH);
        for (int e = 0; e < d; ++e) sew[e * NH + h] *= inv;
    }
    __syncthreads();

    const int h = tid >> 5;
    const int f0 = (tid * 4) & 127;
    float a0 = 0.0f, a1 = 0.0f, a2 = 0.0f, a3 = 0.0f;
    for (int ch = 0; ch < d; ch += 32) {
        const int cnt = min(32, d - ch);
        for (int idx = tid; idx < cnt * 16; idx += 256) {
            int row = idx >> 4, c8 = idx & 15;
            *(f16x8*)(sx + row * 128 + c8 * 8) = *(const f16x8*)(X + (size_t)sed[ch + row] * 128 + c8 * 8);
        }
        __syncthreads();
        for (int e = 0; e < cnt; ++e) {
            float w = sew[(ch + e) * NH + h];
            f16x4 xv = *(const f16x4*)(sx + e * 128 + f0);
            a0 += w * (float)xv[0];
            a1 += w * (float)xv[1];
            a2 += w * (float)xv[2];
            a3 += w * (float)xv[3];
        }
        __syncthreads();
    }
    f16* Zr = Z + (size_t)n * 1184;
    f16x4 o; o[0] = (f16)a0; o[1] = (f16)a1; o[2] = (f16)a2; o[3] = (f16)a3;
    *(f16x4*)(Zr + tid * 4) = o;
    if (tid < 16) *(f16x8*)(Zr + 1024 + tid * 8) = *(const f16x8*)(X + (size_t)n * 128 + tid * 8);
    if (tid >= 32 && tid < 40) {
        int hh = tid - 32;
        float s = 0.0f;
        for (int e = 0; e < d; ++e) s += sew[e * NH + hh];
        Zr[1152 + hh] = (f16)s;
    }
    if (tid >= 64 && tid < 88) Zr[1160 + (tid - 64)] = (f16)0.0f;
}

// ---------------- layers 2,3: logits + softmax + V aggregation + skip + ELU, fused ----
__global__ __launch_bounds__(256) void edge_node(const f16* __restrict__ QKVS,
                                                 const float* __restrict__ Sf,
                                                 const int* __restrict__ offs,
                                                 const int* __restrict__ srcCSR,
                                                 float* __restrict__ hout, f16* __restrict__ houth,
                                                 int Np, int C, int hc, float scale, int writeHout) {
    const int n = blockIdx.x;
    const int e0 = offs[n];
    int d = offs[n + 1] - e0;
    if (d > 256) d = 256;

    __shared__ __align__(16) f16 sq[4096];
    __shared__ float sew[256 * NH];
    __shared__ int sed[256];
    __shared__ float sred[512];
    const int tid = threadIdx.x;

    const f16x8* qg = (const f16x8*)(QKVS + (size_t)n * Np);
    const int qchunks = hc >> 3;
    for (int c = tid; c < qchunks; c += 256) ((f16x8*)sq)[c] = qg[c];
    for (int e = tid; e < d; e += 256) sed[e] = srcCSR[e0 + e];
    __syncthreads();

    {
        const int wv = tid >> 6, lane = tid & 63;
        const int cph = C >> 3;
        const int passes = (hc >> 9) ? (hc >> 9) : 1;
        for (int e = wv; e < d; e += 4) {
            const f16x8* kg = (const f16x8*)(QKVS + (size_t)sed[e] * Np + hc);
            for (int p = 0; p < passes; ++p) {
                const int ci = p * 64 + lane;
                f16x8 qv = ((const f16x8*)sq)[ci];
                f16x8 kv = kg[ci];
                float acc = 0.0f;
#pragma unroll
                for (int t = 0; t < 8; ++t) acc += (float)qv[t] * (float)kv[t];
                for (int o = cph >> 1; o > 0; o >>= 1) acc += __shfl_down(acc, o, cph);
                if ((lane & (cph - 1)) == 0) {
                    const int head = ci / cph;
                    sew[e * NH + head] = acc * scale;
                }
            }
        }
    }
    __syncthreads();

    if (tid < NH) {
        const int h = tid;
        float m = -3.0e38f;
        for (int e = 0; e < d; ++e) m = fmaxf(m, sew[e * NH + h]);
        float den = 0.0f;
        for (int e = 0; e < d; ++e) {
            float ex = __expf(sew[e * NH + h] - m);
            sew[e * NH + h] = ex;
            den += ex;
        }
        float inv = 1.0f / (fmaxf(den, 1e-16f) * (float)NH);
        for (int e = 0; e < d; ++e) sew[e * NH + h] *= inv;
    }
    __syncthreads();

    const int half = C >> 1;
    const int cp = tid & (half - 1);
    const int grp = tid / half;
    const int ngr = 256 / half;
    float a0 = 0.0f, a1 = 0.0f;
    for (int e = grp; e < d; e += ngr) {
        const unsigned int* vp = (const unsigned int*)(QKVS + (size_t)sed[e] * Np + 2 * hc);
#pragma unroll
        for (int h = 0; h < NH; ++h) {
            float w = sew[e * NH + h];
            f16x2 vv = __builtin_bit_cast(f16x2, vp[((h * C) >> 1) + cp]);
            a0 += w * (float)vv.x;
            a1 += w * (float)vv.y;
        }
    }
    if (ngr > 1) {
        sred[tid] = a0;
        sred[256 + tid] = a1;
        __syncthreads();
        if (grp == 0) {
            for (int g = 1; g < ngr; ++g) {
                a0 += sred[g * half + cp];
                a1 += sred[256 + g * half + cp];
            }
        }
    }
    if (grp == 0) {
        const int c = cp * 2;
        const float* Sp = Sf + (size_t)n * C;
        float o0 = a0 + Sp[c];
        float o1 = a1 + Sp[c + 1];
        o0 = o0 > 0.0f ? o0 : (__expf(o0) - 1.0f);
        o1 = o1 > 0.0f ? o1 : (__expf(o1) - 1.0f);
        if (writeHout) {
            hout[(size_t)n * C + c] = o0;
            hout[(size_t)n * C + c + 1] = o1;
        }
        houth[(size_t)n * C + c] = (f16)o0;
        houth[(size_t)n * C + c + 1] = (f16)o1;
    }
}

// ---------------- fused pooling + final FC ----------------
__global__ __launch_bounds__(256) void pool_graph(const float* __restrict__ h,
                                                  const float* __restrict__ gw, const float* __restrict__ gb,
                                                  const float* __restrict__ fcw, const float* __restrict__ fcb,
                                                  const int* __restrict__ goffs,
                                                  float* __restrict__ gbuf, float* __restrict__ out) {
    const int g = blockIdx.x;
    const int s = goffs[g], e = goffs[g + 1];
    const int tid = threadIdx.x;
    const int wv = tid >> 6, lane = tid & 63;

    __shared__ float red[256];
    __shared__ float pl[64];
    __shared__ float sden;

    if (e == s) {
        if (tid < 10) out[g * 10 + tid] = fcb[tid];
        return;
    }

    const float gwl = gw[lane];
    for (int n = s + wv; n < e; n += 4) {
        float acc = h[(size_t)n * 64 + lane] * gwl;
#pragma unroll
        for (int o = 32; o > 0; o >>= 1) acc += __shfl_down(acc, o, 64);
        if (lane == 0) gbuf[n] = acc + gb[0];
    }
    __syncthreads();

    float m = -3.0e38f;
    for (int n = s + tid; n < e; n += 256) m = fmaxf(m, gbuf[n]);
    red[tid] = m;
    __syncthreads();
    for (int o = 128; o > 0; o >>= 1) {
        if (tid < o) red[tid] = fmaxf(red[tid], red[tid + o]);
        __syncthreads();
    }
    m = red[0];
    __syncthreads();

    float sum = 0.0f;
    for (int n = s + tid; n < e; n += 256) {
        float ex = __expf(gbuf[n] - m);
        gbuf[n] = ex;
        sum += ex;
    }
    red[tid] = sum;
    __syncthreads();
    for (int o = 128; o > 0; o >>= 1) {
        if (tid < o) red[tid] += red[tid + o];
        __syncthreads();
    }
    if (tid == 0) sden = 1.0f / fmaxf(red[0], 1e-16f);
    __syncthreads();

    float acc = 0.0f;
    for (int n = s + wv; n < e; n += 4) acc += gbuf[n] * h[(size_t)n * 64 + lane];
    red[tid] = acc;
    __syncthreads();
    if (wv == 0) pl[lane] = (red[lane] + red[64 + lane] + red[128 + lane] + red[192 + lane]) * sden;
    __syncthreads();

    if (tid < 10) {
        float o = fcb[tid];
#pragma unroll
        for (int c = 0; c < 64; ++c) o += pl[c] * fcw[c * 10 + tid];
        out[g * 10 + tid] = o;
    }
}

// ---------------- host ----------------
extern "C" void kernel_launch(void* const* d_in, const int* in_sizes, int n_in,
                              void* d_out, int out_size, void* d_ws, size_t ws_size,
                              hipStream_t stream) {
    const float* x   = (const float*)d_in[0];
    const int* ei    = (const int*)d_in[1];
    const int* src   = ei;
    const int* dst   = ei + NE;
    const int* batch = (const int*)d_in[2];

    struct LayerW { int fin, C, hc; const float *qw,*qb,*kw,*kb,*vw,*vb,*sw,*sb; };
    LayerW LW[3];
    const int fins[3] = {128, 512, 256};
    const int Cs[3]   = {512, 256, 64};
    for (int l = 0; l < 3; ++l) {
        int b = 3 + 8 * l;
        LW[l].fin = fins[l]; LW[l].C = Cs[l]; LW[l].hc = Cs[l] * NH;
        LW[l].qw = (const float*)d_in[b + 0]; LW[l].qb = (const float*)d_in[b + 1];
        LW[l].kw = (const float*)d_in[b + 2]; LW[l].kb = (const float*)d_in[b + 3];
        LW[l].vw = (const float*)d_in[b + 4]; LW[l].vb = (const float*)d_in[b + 5];
        LW[l].sw = (const float*)d_in[b + 6]; LW[l].sb = (const float*)d_in[b + 7];
    }
    const float* gate_w = (const float*)d_in[27];
    const float* gate_b = (const float*)d_in[28];
    const float* fc_w   = (const float*)d_in[29];
    const float* fc_b   = (const float*)d_in[30];

    size_t off = 0;
    char* ws = (char*)d_ws;
    auto alloc = [&](size_t bytes) -> void* {
        void* p = ws + off;
        off = (off + bytes + 255) & ~(size_t)255;
        return p;
    };
    f16* BtL2   = (f16*)alloc((size_t)6400 * 512 * sizeof(f16));
    f16* BtL3   = (f16*)alloc((size_t)1664 * 256 * sizeof(f16));
    f16* BtZ    = (f16*)alloc((size_t)512 * 1184 * sizeof(f16));
    float* biasL2 = (float*)alloc(6400 * sizeof(float));
    float* biasL3 = (float*)alloc(1664 * sizeof(float));
    float* biasZ  = (float*)alloc(512 * sizeof(float));
    f16* QKbuf  = (f16*)alloc((size_t)NN * 6400 * sizeof(f16));    // Y / Q|K|V|S per phase
    f16* Zbuf   = (f16*)alloc((size_t)NN * 1184 * sizeof(f16));    // layer-1 Z rows
    float* Sf   = (float*)alloc((size_t)NN * 256 * sizeof(float));
    f16* xh     = (f16*)alloc((size_t)NN * 128 * sizeof(f16));
    f16* houth  = (f16*)alloc((size_t)NN * 512 * sizeof(f16));
    float* hf   = (float*)alloc((size_t)NN * 64 * sizeof(float));
    f16* qw16   = (f16*)alloc((size_t)128 * 4096 * sizeof(f16));
    f16* kw16   = (f16*)alloc((size_t)128 * 4096 * sizeof(f16));
    f16* BtY    = (f16*)alloc((size_t)1152 * 128 * sizeof(f16));
    int*   deg   = (int*)alloc(NN * sizeof(int));
    float* zbias = (float*)alloc(512 * sizeof(float));
    float* biasY = (float*)alloc(1152 * sizeof(float));
    size_t zspan = (size_t)((char*)(biasY + 1152) - (char*)deg);
    int* offs   = (int*)alloc((NN + 1) * sizeof(int));
    int* cursor = (int*)alloc(NN * sizeof(int));
    int* srcCSR = (int*)alloc(NE * sizeof(int));
    int* goffs  = (int*)alloc((NG + 1) * sizeof(int));
    float* gbuf = (float*)alloc(NN * sizeof(float));
    if (off > ws_size) return;

    hipMemsetAsync(deg, 0, zspan, stream);
    hist_kernel<<<(NE + 255) / 256, 256, 0, stream>>>(dst, deg, NE);
    scan_goffs<<<2, 1024, 0, stream>>>(deg, offs, cursor, batch, goffs);
    scatter_kernel<<<(NE + 255) / 256, 256, 0, stream>>>(src, dst, cursor, srcCSR, NE);
    sort_csr<<<(NN + 255) / 256, 256, 0, stream>>>(offs, srcCSR);

    {
        int na = NN * 128, nb2 = 128 * 4096, nc = 128 * 4096;
        cvt3_kernel<<<(na + nb2 + nc + 255) / 256, 256, 0, stream>>>(x, xh, na,
                                                                     LW[0].qw, qw16, nb2,
                                                                     LW[0].kw, kw16, nc);
    }
    prep4t2<<<dim3(8, 100, 2), 256, 0, stream>>>(
        LW[1].qw, 2048, LW[1].kw, 2048, LW[1].vw, 2048, LW[1].sw, 256,
        LW[1].qb, LW[1].kb, LW[1].vb, LW[1].sb, BtL2, biasL2, 512, 6400,
        LW[2].qw, 512, LW[2].kw, 512, LW[2].vw, 512, LW[2].sw, 64,
        LW[2].qb, LW[2].kb, LW[2].vb, LW[2].sb, BtL3, biasL3, 256, 1664);
    prepZB<<<dim3(37, 8), 256, 0, stream>>>(LW[0].vw, LW[0].sw, LW[0].vb, LW[0].sb, BtZ, biasZ);

    const int grid_m = 80;   // mult of 8: XCD-stable across y-passes

    // ---- layer 1: Y-trick alpha + fused softmax + Z aggregation + Z-GEMM ----
    {
        const int fin = 128, hc = 4096, NtotY = 1152;
        const float scale = 1.0f / sqrtf(512.0f);
        dim3 gm(1, 1, 8);
        gemm128<<<gm, 256, 0, stream>>>(kw16, hc, 512, qw16, hc, 512, zbias,
                                        BtY, fin, fin * fin, nullptr, fin, fin, 512, 0, 0, 0);
        prepU<<<(fin * 16 + 3) / 4, 256, 0, stream>>>(LW[0].qw, LW[0].qb, LW[0].kw, LW[0].kb,
                                                      BtY, biasY, fin, hc, 512);
        dim3 gy(grid_m, NtotY / 128);
        gemm128<<<gy, 256, 0, stream>>>(xh, fin, 0, BtY, fin, 0, biasY,
                                        QKbuf, NtotY, 0, nullptr, NN, NtotY, fin, 0, 0, 0);
        alpha_zagg<<<NN, 256, 0, stream>>>(QKbuf, xh, offs, srcCSR, Zbuf, NtotY, scale);
        dim3 gz(grid_m, 4);
        gemm128<<<gz, 256, 0, stream>>>(Zbuf, 1184, 0, BtZ, 1184, 0, biasZ,
                                        houth, 512, 0, nullptr, NN, 512, 1184, 0, 0, 1);
    }
    // ---- layers 2,3: fused Q|K|V|S GEMM + fused edge/node kernel ----
    const f16* Acur = houth;
    for (int l = 1; l < 3; ++l) {
        const int K = LW[l].fin, C = LW[l].C, hc = LW[l].hc;
        const float scale = 1.0f / sqrtf((float)C);
        const int Np = (3 * hc + C + 127) & ~127;   // L2: 6400, L3: 1664
        f16* Bt = (l == 1) ? BtL2 : BtL3;
        float* bias = (l == 1) ? biasL2 : biasL3;
        dim3 gq(grid_m, Np / 128);
        gemm128<<<gq, 256, 0, stream>>>(Acur, K, 0, Bt, K, 0, bias,
                                        QKbuf, Np, 0, Sf, NN, Np, K, 3 * hc, C, 0);
        edge_node<<<NN, 256, 0, stream>>>(QKbuf, Sf, offs, srcCSR, hf, houth,
                                          Np, C, hc, scale, l == 2 ? 1 : 0);
        Acur = houth;
    }

    pool_graph<<<NG, 256, 0, stream>>>(hf, gate_w, gate_b, fc_w, fc_b, goffs, gbuf, (float*)d_out);
}